// Round 1
// baseline (647.784 us; speedup 1.0000x reference)
//
#include <hip/hip_runtime.h>
#include <hip/hip_bf16.h>
#include <stdint.h>

#define B_SZ 2
#define S_LEN 2048
#define D_MODEL 2048
#define NH 32
#define NG 8
#define HGRP 4
#define DHEAD 64
#define KV_DIM 512       // NG*DHEAD
#define M_TOK 4096       // B_SZ*S_LEN

typedef __attribute__((ext_vector_type(8))) short bf16x8;
typedef __attribute__((ext_vector_type(4))) float f32x4;

__device__ inline unsigned short f2bf(float x) {
    uint32_t u = __builtin_bit_cast(uint32_t, x);
    uint32_t r = (u + 0x7fffu + ((u >> 16) & 1u)) >> 16;
    return (unsigned short)r;
}

__device__ inline void async_copy16(const void* g, void* l) {
    __builtin_amdgcn_global_load_lds(
        (const __attribute__((address_space(1))) void*)g,
        (__attribute__((address_space(3))) void*)l,
        16, 0, 0);
}

// ---------------- f32 -> bf16 convert, 8 elems/thread ----------------
__global__ __launch_bounds__(256) void cvt_kernel(const float* __restrict__ in,
                                                  unsigned short* __restrict__ out,
                                                  int n8) {
    int i = blockIdx.x * 256 + threadIdx.x;
    if (i >= n8) return;
    const float4* p = reinterpret_cast<const float4*>(in) + (size_t)i * 2;
    float4 a = p[0], b = p[1];
    union { unsigned short u[8]; uint4 v; } r;
    r.u[0] = f2bf(a.x); r.u[1] = f2bf(a.y); r.u[2] = f2bf(a.z); r.u[3] = f2bf(a.w);
    r.u[4] = f2bf(b.x); r.u[5] = f2bf(b.y); r.u[6] = f2bf(b.z); r.u[7] = f2bf(b.w);
    reinterpret_cast<uint4*>(out)[i] = r.v;
}

// ---------------- GEMM: C[M][N] = A[M][K] * Bm[N][K]^T (bf16 in, f32 acc) ----
// 128x128 tile, BK=32, 4 waves, each wave 64x64 (4x4 frags of 16x16x32).
template<int OUT_F32>
__global__ __launch_bounds__(256) void gemm_bt(const unsigned short* __restrict__ A,
                                               const unsigned short* __restrict__ Bm,
                                               void* __restrict__ Cout,
                                               int M, int N, int K) {
    __shared__ unsigned short As[128 * 32];
    __shared__ unsigned short Bs[128 * 32];
    int tid = threadIdx.x;
    int lane = tid & 63;
    int w = tid >> 6;
    int wr = w >> 1, wc = w & 1;
    int l15 = lane & 15, l4 = lane >> 4;
    int m0 = blockIdx.x * 128;
    int n0 = blockIdx.y * 128;
    f32x4 acc[4][4] = {};

    for (int kt = 0; kt < K; kt += 32) {
#pragma unroll
        for (int j = 0; j < 2; ++j) {
            int c = j * 256 + tid;
            int row = c >> 2, col = (c & 3) * 8;
            async_copy16(A + (size_t)(m0 + row) * K + kt + col, &As[c * 8]);
        }
#pragma unroll
        for (int j = 0; j < 2; ++j) {
            int c = j * 256 + tid;
            int row = c >> 2, col = (c & 3) * 8;
            async_copy16(Bm + (size_t)(n0 + row) * K + kt + col, &Bs[c * 8]);
        }
        __syncthreads();
        bf16x8 af[4], bfr[4];
#pragma unroll
        for (int i = 0; i < 4; ++i) {
            int row = wr * 64 + i * 16 + l15;
            af[i] = *reinterpret_cast<const bf16x8*>(&As[row * 32 + l4 * 8]);
            int col = wc * 64 + i * 16 + l15;
            bfr[i] = *reinterpret_cast<const bf16x8*>(&Bs[col * 32 + l4 * 8]);
        }
#pragma unroll
        for (int i = 0; i < 4; ++i)
#pragma unroll
            for (int jn = 0; jn < 4; ++jn)
                acc[i][jn] = __builtin_amdgcn_mfma_f32_16x16x32_bf16(af[i], bfr[jn], acc[i][jn], 0, 0, 0);
        __syncthreads();
    }
#pragma unroll
    for (int i = 0; i < 4; ++i) {
        int row = m0 + wr * 64 + i * 16 + l4 * 4;
#pragma unroll
        for (int jn = 0; jn < 4; ++jn) {
            int col = n0 + wc * 64 + jn * 16 + l15;
#pragma unroll
            for (int r = 0; r < 4; ++r) {
                if (OUT_F32)
                    ((float*)Cout)[(size_t)(row + r) * N + col] = acc[i][jn][r];
                else
                    ((unsigned short*)Cout)[(size_t)(row + r) * N + col] = f2bf(acc[i][jn][r]);
            }
        }
    }
}

// ---------------- vp [B,S,G,DH] -> vpT [B,G,DH,S] ----------------
__global__ __launch_bounds__(256) void transpose_v(const unsigned short* __restrict__ vp,
                                                   unsigned short* __restrict__ vpT) {
    int c = blockIdx.x * 256 + threadIdx.x;   // B*G*DH*(S/8) = 262144 chunks
    int s8 = c & (S_LEN / 8 - 1);
    int rest = c >> 8;
    int dh = rest & 63;
    int bg = rest >> 6;
    int b = bg >> 3, g = bg & 7;
    union { unsigned short u[8]; uint4 v; } r;
#pragma unroll
    for (int j = 0; j < 8; ++j) {
        int s = s8 * 8 + j;
        r.u[j] = vp[(size_t)(b * S_LEN + s) * KV_DIM + g * DHEAD + dh];
    }
    reinterpret_cast<uint4*>(vpT)[c] = r.v;
}

// ---------------- flash attention (causal, GQA) ----------------
// grid: (S/128, B*H). 4 waves, each owns 32 query rows. KV tile = 128.
__global__ __launch_bounds__(256) void attn_kernel(const unsigned short* __restrict__ qp,
                                                   const unsigned short* __restrict__ kp,
                                                   const unsigned short* __restrict__ vpT,
                                                   unsigned short* __restrict__ attn_out) {
    __shared__ unsigned short Ks[128 * 64];    // [t][dh], XOR-swizzled
    __shared__ unsigned short Vs[64 * 128];    // [dh][t], XOR-swizzled
    __shared__ unsigned short Ps[128 * 128];   // [m][t],  XOR-swizzled

    int tid = threadIdx.x;
    int lane = tid & 63;
    int w = tid >> 6;
    int l15 = lane & 15, l4 = lane >> 4;
    int qi = blockIdx.x;
    int bh = blockIdx.y;
    int b = bh >> 5;
    int head = bh & 31;
    int g = head >> 2;
    int s0 = qi * 128;

    // Q fragments in registers: rows w*32 + mi*16 + l15, k = ks*32 + l4*8
    bf16x8 qf[2][2];
#pragma unroll
    for (int mi = 0; mi < 2; ++mi)
#pragma unroll
        for (int ks = 0; ks < 2; ++ks) {
            const unsigned short* gq = qp + (size_t)(b * S_LEN + s0 + w * 32 + mi * 16 + l15) * D_MODEL
                                       + head * DHEAD + ks * 32 + l4 * 8;
            qf[mi][ks] = *reinterpret_cast<const bf16x8*>(gq);
        }

    float mrun[2][4], lrun[2][4];
    f32x4 o[2][4] = {};
#pragma unroll
    for (int mi = 0; mi < 2; ++mi)
#pragma unroll
        for (int r = 0; r < 4; ++r) { mrun[mi][r] = -3.0e38f; lrun[mi][r] = 0.f; }

    for (int j = 0; j <= qi; ++j) {
        int t0 = j * 128;
        // stage K tile [128][64] swizzled
        for (int c = tid; c < 1024; c += 256) {
            int t = c >> 3, kg = c & 7;
            const uint4* src = reinterpret_cast<const uint4*>(
                kp + (size_t)(b * S_LEN + t0 + t) * KV_DIM + g * DHEAD + kg * 8);
            int dst = t * 128 + ((kg * 16) ^ ((t & 7) << 4));
            *reinterpret_cast<uint4*>((char*)Ks + dst) = *src;
        }
        // stage V^T tile [64][128] swizzled
        for (int c = tid; c < 1024; c += 256) {
            int dh = c >> 4, tg = c & 15;
            const uint4* src = reinterpret_cast<const uint4*>(
                vpT + (size_t)((b * NG + g) * DHEAD + dh) * S_LEN + t0 + tg * 8);
            int dst = dh * 256 + ((tg * 16) ^ ((dh & 7) << 4));
            *reinterpret_cast<uint4*>((char*)Vs + dst) = *src;
        }
        __syncthreads();

        // S = Q K^T   [m][t]
        f32x4 sa[2][8] = {};
#pragma unroll
        for (int nj = 0; nj < 8; ++nj) {
            int trow = nj * 16 + l15;
#pragma unroll
            for (int ks = 0; ks < 2; ++ks) {
                int kof = (ks * 32 + l4 * 8) * 2;
                bf16x8 kf = *reinterpret_cast<const bf16x8*>(
                    (char*)Ks + trow * 128 + (kof ^ ((trow & 7) << 4)));
#pragma unroll
                for (int mi = 0; mi < 2; ++mi)
                    sa[mi][nj] = __builtin_amdgcn_mfma_f32_16x16x32_bf16(qf[mi][ks], kf, sa[mi][nj], 0, 0, 0);
            }
        }

        bool diag = (j == qi);
#pragma unroll
        for (int mi = 0; mi < 2; ++mi) {
#pragma unroll
            for (int r = 0; r < 4; ++r) {
                int m = w * 32 + mi * 16 + l4 * 4 + r;
                int sg = s0 + m;
                float pv[8];
                float rowmax = -3.0e38f;
#pragma unroll
                for (int nj = 0; nj < 8; ++nj) {
                    float v = sa[mi][nj][r] * 0.125f;
                    if (diag) {
                        int t = t0 + nj * 16 + l15;
                        if (t > sg) v = -1.0e30f;
                    }
                    pv[nj] = v;
                    rowmax = fmaxf(rowmax, v);
                }
#pragma unroll
                for (int msk = 1; msk < 16; msk <<= 1)
                    rowmax = fmaxf(rowmax, __shfl_xor(rowmax, msk, 64));
                float mnew = fmaxf(mrun[mi][r], rowmax);
                float corr = __expf(mrun[mi][r] - mnew);
                float rs = 0.f;
#pragma unroll
                for (int nj = 0; nj < 8; ++nj) {
                    float p = __expf(pv[nj] - mnew);
                    pv[nj] = p;
                    rs += p;
                }
#pragma unroll
                for (int msk = 1; msk < 16; msk <<= 1)
                    rs += __shfl_xor(rs, msk, 64);
                mrun[mi][r] = mnew;
                lrun[mi][r] = lrun[mi][r] * corr + rs;
#pragma unroll
                for (int nj4 = 0; nj4 < 4; ++nj4)
                    o[mi][nj4][r] *= corr;
                // write P row to LDS (bf16, swizzled)
#pragma unroll
                for (int nj = 0; nj < 8; ++nj) {
                    int col = nj * 16 + l15;
                    int byte_ = m * 256 + ((col * 2) ^ ((m & 7) << 4));
                    *reinterpret_cast<unsigned short*>((char*)Ps + byte_) = f2bf(pv[nj]);
                }
            }
        }
        __syncthreads();   // P fully written (and K/V reads done for safety)

        // O += P V   [m][dh]
#pragma unroll
        for (int ks2 = 0; ks2 < 4; ++ks2) {
            int kof = (ks2 * 32 + l4 * 8) * 2;
            bf16x8 pf[2];
#pragma unroll
            for (int mi = 0; mi < 2; ++mi) {
                int rowm = w * 32 + mi * 16 + l15;
                pf[mi] = *reinterpret_cast<const bf16x8*>(
                    (char*)Ps + rowm * 256 + (kof ^ ((rowm & 7) << 4)));
            }
#pragma unroll
            for (int nj = 0; nj < 4; ++nj) {
                int vrow = nj * 16 + l15;
                bf16x8 vf = *reinterpret_cast<const bf16x8*>(
                    (char*)Vs + vrow * 256 + (kof ^ ((vrow & 7) << 4)));
#pragma unroll
                for (int mi = 0; mi < 2; ++mi)
                    o[mi][nj] = __builtin_amdgcn_mfma_f32_16x16x32_bf16(pf[mi], vf, o[mi][nj], 0, 0, 0);
            }
        }
        __syncthreads();   // before next tile overwrites K/V
    }

    // normalize + store attn output (bf16) in [b, s, head*64+dh] layout
#pragma unroll
    for (int mi = 0; mi < 2; ++mi) {
#pragma unroll
        for (int r = 0; r < 4; ++r) {
            int m = w * 32 + mi * 16 + l4 * 4 + r;
            float inv = 1.0f / lrun[mi][r];
#pragma unroll
            for (int nj = 0; nj < 4; ++nj) {
                int dh = nj * 16 + l15;
                attn_out[(size_t)(b * S_LEN + s0 + m) * D_MODEL + head * DHEAD + dh] =
                    f2bf(o[mi][nj][r] * inv);
            }
        }
    }
}

// ---------------- host launch ----------------
extern "C" void kernel_launch(void* const* d_in, const int* in_sizes, int n_in,
                              void* d_out, int out_size, void* d_ws, size_t ws_size,
                              hipStream_t stream) {
    const float* q     = (const float*)d_in[0];
    const float* k     = (const float*)d_in[1];
    const float* v     = (const float*)d_in[2];
    // d_in[3] = causal mask, known analytically -> ignored
    const float* w_q   = (const float*)d_in[4];
    const float* w_k   = (const float*)d_in[5];
    const float* w_v   = (const float*)d_in[6];
    const float* w_out = (const float*)d_in[7];

    char* ws = (char*)d_ws;
    size_t off = 0;
    auto alloc = [&](size_t n) { char* p = ws + off; off += (n + 255) & ~(size_t)255; return p; };
    unsigned short* xb  = (unsigned short*)alloc((size_t)M_TOK * D_MODEL * 2);  // q/k/v bf16 (reused), later vpT
    unsigned short* wb8 = (unsigned short*)alloc((size_t)D_MODEL * D_MODEL * 2); // w_q then w_out
    unsigned short* wkb = (unsigned short*)alloc((size_t)KV_DIM * D_MODEL * 2);
    unsigned short* wvb = (unsigned short*)alloc((size_t)KV_DIM * D_MODEL * 2);
    unsigned short* qpb = (unsigned short*)alloc((size_t)M_TOK * D_MODEL * 2);
    unsigned short* kpb = (unsigned short*)alloc((size_t)M_TOK * KV_DIM * 2);
    unsigned short* vpb = (unsigned short*)alloc((size_t)M_TOK * KV_DIM * 2);
    unsigned short* vtb = (unsigned short*)alloc((size_t)M_TOK * KV_DIM * 2);
    unsigned short* aob = (unsigned short*)alloc((size_t)M_TOK * D_MODEL * 2);

    dim3 blk(256);
    int n8_qkv = M_TOK * D_MODEL / 8;       // 1048576
    int n8_wq  = D_MODEL * D_MODEL / 8;     // 524288
    int n8_wkv = KV_DIM * D_MODEL / 8;      // 131072

    // weights
    cvt_kernel<<<dim3(n8_wq / 256), blk, 0, stream>>>(w_q, wb8, n8_wq);
    cvt_kernel<<<dim3(n8_wkv / 256), blk, 0, stream>>>(w_k, wkb, n8_wkv);
    cvt_kernel<<<dim3(n8_wkv / 256), blk, 0, stream>>>(w_v, wvb, n8_wkv);

    // q projection
    cvt_kernel<<<dim3(n8_qkv / 256), blk, 0, stream>>>(q, xb, n8_qkv);
    gemm_bt<0><<<dim3(M_TOK / 128, D_MODEL / 128), blk, 0, stream>>>(xb, wb8, qpb, M_TOK, D_MODEL, D_MODEL);
    // k projection
    cvt_kernel<<<dim3(n8_qkv / 256), blk, 0, stream>>>(k, xb, n8_qkv);
    gemm_bt<0><<<dim3(M_TOK / 128, KV_DIM / 128), blk, 0, stream>>>(xb, wkb, kpb, M_TOK, KV_DIM, D_MODEL);
    // v projection
    cvt_kernel<<<dim3(n8_qkv / 256), blk, 0, stream>>>(v, xb, n8_qkv);
    gemm_bt<0><<<dim3(M_TOK / 128, KV_DIM / 128), blk, 0, stream>>>(xb, wvb, vpb, M_TOK, KV_DIM, D_MODEL);

    // w_out conversion (wb8 is free after q projection)
    cvt_kernel<<<dim3(n8_wq / 256), blk, 0, stream>>>(w_out, wb8, n8_wq);

    // V transpose for PV operand
    transpose_v<<<dim3(262144 / 256), blk, 0, stream>>>(vpb, vtb);

    // attention
    attn_kernel<<<dim3(S_LEN / 128, B_SZ * NH), blk, 0, stream>>>(qpb, kpb, vtb, aob);

    // output projection -> f32 d_out
    gemm_bt<1><<<dim3(M_TOK / 128, D_MODEL / 128), blk, 0, stream>>>(aob, wb8, (float*)d_out, M_TOK, D_MODEL, D_MODEL);
}

// Round 2
// 360.291 us; speedup vs baseline: 1.7979x; 1.7979x over previous
//
#include <hip/hip_runtime.h>
#include <hip/hip_bf16.h>
#include <stdint.h>

#define B_SZ 2
#define S_LEN 2048
#define D_MODEL 2048
#define NH 32
#define NG 8
#define HGRP 4
#define DHEAD 64
#define KV_DIM 512       // NG*DHEAD
#define M_TOK 4096       // B_SZ*S_LEN
#define KVB 64           // attention KV tile
#define N_ITEMS 1024     // 16 q-tiles * 64 (b,head)

typedef __attribute__((ext_vector_type(8))) short bf16x8;
typedef __attribute__((ext_vector_type(4))) float f32x4;

__device__ inline unsigned short f2bf(float x) {
    uint32_t u = __builtin_bit_cast(uint32_t, x);
    uint32_t r = (u + 0x7fffu + ((u >> 16) & 1u)) >> 16;
    return (unsigned short)r;
}

__device__ inline uint32_t pk2(float a, float b) {
    return (uint32_t)f2bf(a) | ((uint32_t)f2bf(b) << 16);
}

__device__ inline void async_copy16(const void* g, void* l) {
    __builtin_amdgcn_global_load_lds(
        (const __attribute__((address_space(1))) void*)g,
        (__attribute__((address_space(3))) void*)l,
        16, 0, 0);
}

// ---------------- f32 -> bf16 convert, 8 elems/thread ----------------
__global__ __launch_bounds__(256) void cvt_kernel(const float* __restrict__ in,
                                                  unsigned short* __restrict__ out,
                                                  int n8) {
    int i = blockIdx.x * 256 + threadIdx.x;
    if (i >= n8) return;
    const float4* p = reinterpret_cast<const float4*>(in) + (size_t)i * 2;
    float4 a = p[0], b = p[1];
    union { unsigned short u[8]; uint4 v; } r;
    r.u[0] = f2bf(a.x); r.u[1] = f2bf(a.y); r.u[2] = f2bf(a.z); r.u[3] = f2bf(a.w);
    r.u[4] = f2bf(b.x); r.u[5] = f2bf(b.y); r.u[6] = f2bf(b.z); r.u[7] = f2bf(b.w);
    reinterpret_cast<uint4*>(out)[i] = r.v;
}

// ---------------- GEMM: C[M][N] = A[M][K] * Bm[N][K]^T (bf16 in, f32 acc) ----
template<int OUT_F32>
__global__ __launch_bounds__(256) void gemm_bt(const unsigned short* __restrict__ A,
                                               const unsigned short* __restrict__ Bm,
                                               void* __restrict__ Cout,
                                               int M, int N, int K) {
    __shared__ unsigned short As[128 * 32];
    __shared__ unsigned short Bs[128 * 32];
    int tid = threadIdx.x;
    int lane = tid & 63;
    int w = tid >> 6;
    int wr = w >> 1, wc = w & 1;
    int l15 = lane & 15, l4 = lane >> 4;
    int m0 = blockIdx.x * 128;
    int n0 = blockIdx.y * 128;
    f32x4 acc[4][4] = {};

    for (int kt = 0; kt < K; kt += 32) {
#pragma unroll
        for (int j = 0; j < 2; ++j) {
            int c = j * 256 + tid;
            int row = c >> 2, col = (c & 3) * 8;
            async_copy16(A + (size_t)(m0 + row) * K + kt + col, &As[c * 8]);
        }
#pragma unroll
        for (int j = 0; j < 2; ++j) {
            int c = j * 256 + tid;
            int row = c >> 2, col = (c & 3) * 8;
            async_copy16(Bm + (size_t)(n0 + row) * K + kt + col, &Bs[c * 8]);
        }
        __syncthreads();
        bf16x8 af[4], bfr[4];
#pragma unroll
        for (int i = 0; i < 4; ++i) {
            int row = wr * 64 + i * 16 + l15;
            af[i] = *reinterpret_cast<const bf16x8*>(&As[row * 32 + l4 * 8]);
            int col = wc * 64 + i * 16 + l15;
            bfr[i] = *reinterpret_cast<const bf16x8*>(&Bs[col * 32 + l4 * 8]);
        }
#pragma unroll
        for (int i = 0; i < 4; ++i)
#pragma unroll
            for (int jn = 0; jn < 4; ++jn)
                acc[i][jn] = __builtin_amdgcn_mfma_f32_16x16x32_bf16(af[i], bfr[jn], acc[i][jn], 0, 0, 0);
        __syncthreads();
    }
#pragma unroll
    for (int i = 0; i < 4; ++i) {
        int row = m0 + wr * 64 + i * 16 + l4 * 4;
#pragma unroll
        for (int jn = 0; jn < 4; ++jn) {
            int col = n0 + wc * 64 + jn * 16 + l15;
#pragma unroll
            for (int r = 0; r < 4; ++r) {
                if (OUT_F32)
                    ((float*)Cout)[(size_t)(row + r) * N + col] = acc[i][jn][r];
                else
                    ((unsigned short*)Cout)[(size_t)(row + r) * N + col] = f2bf(acc[i][jn][r]);
            }
        }
    }
}

// ---------------- vp [B,S,G,DH] -> vpT [B,G,DH,S] ----------------
__global__ __launch_bounds__(256) void transpose_v(const unsigned short* __restrict__ vp,
                                                   unsigned short* __restrict__ vpT) {
    int c = blockIdx.x * 256 + threadIdx.x;   // B*G*DH*(S/8) = 262144 chunks
    int s8 = c & (S_LEN / 8 - 1);
    int rest = c >> 8;
    int dh = rest & 63;
    int bg = rest >> 6;
    int b = bg >> 3, g = bg & 7;
    union { unsigned short u[8]; uint4 v; } r;
#pragma unroll
    for (int j = 0; j < 8; ++j) {
        int s = s8 * 8 + j;
        r.u[j] = vp[(size_t)(b * S_LEN + s) * KV_DIM + g * DHEAD + dh];
    }
    reinterpret_cast<uint4*>(vpT)[c] = r.v;
}

__global__ void init_counter(unsigned int* c) { *c = 0u; }

// ---------------- flash attention v2 (causal, GQA) ----------------
// Persistent blocks + atomic queue (heavy q-tiles first). 4 waves, each
// owns 32 query rows of a 128-row q-tile. KV tile = 64. Swapped QK^T so
// softmax reduces over 4 lanes and P writes are packed b64. PV computes
// O^T = mfma(V, P) so softmax state stays lane-local (m = lane&15).
__global__ __launch_bounds__(256) void attn_kernel(const unsigned short* __restrict__ qp,
                                                   const unsigned short* __restrict__ kp,
                                                   const unsigned short* __restrict__ vpT,
                                                   unsigned short* __restrict__ attn_out,
                                                   unsigned int* __restrict__ counter) {
    __shared__ __align__(16) unsigned short Ks[KVB * 64];   // [t][dh] swz, 8KB
    __shared__ __align__(16) unsigned short Vs[64 * KVB];   // [dh][t] swz, 8KB
    __shared__ __align__(16) unsigned short Ps[128 * KVB];  // [m][t]  swz, 16KB
    __shared__ int s_item;

    const int tid = threadIdx.x;
    const int lane = tid & 63;
    const int w = tid >> 6;
    const int l15 = lane & 15, l4 = lane >> 4;
    const float SCL = 0.125f * 1.44269504f;   // 1/sqrt(64) * log2(e)

    for (;;) {
        if (tid == 0) s_item = (int)atomicAdd(counter, 1u);
        __syncthreads();
        const int item = s_item;
        if (item >= N_ITEMS) break;
        const int qi = 15 - (item >> 6);      // heavy first
        const int bh = item & 63;
        const int b = bh >> 5, head = bh & 31, g = head >> 2;
        const int s0 = qi * 128;
        const int mmaxw = s0 + w * 32 + 31;   // this wave's max query row

        // Q fragments: row m = l15 (+16mi), k = dh = ks*32 + l4*8
        bf16x8 qf[2][2];
#pragma unroll
        for (int mi = 0; mi < 2; ++mi)
#pragma unroll
            for (int ks = 0; ks < 2; ++ks)
                qf[mi][ks] = *reinterpret_cast<const bf16x8*>(
                    qp + (size_t)(b * S_LEN + s0 + w * 32 + mi * 16 + l15) * D_MODEL
                       + head * DHEAD + ks * 32 + l4 * 8);

        float mrun[2] = {-1e30f, -1e30f};
        float lrun[2] = {0.f, 0.f};
        f32x4 o[2][4] = {};

        const int nt = 2 * (qi + 1);
        for (int j = 0; j < nt; ++j) {
            const int t0 = j * KVB;

            // ---- stage K,V (reg-staged, XOR-swizzled rows) ----
            {
                const int r0 = tid >> 3, c0 = tid & 7;          // chunk 0
                const int r1 = (tid + 256) >> 3, c1 = tid & 7;  // chunk 1
                const uint4 k0 = *reinterpret_cast<const uint4*>(
                    kp + (size_t)(b * S_LEN + t0 + r0) * KV_DIM + g * DHEAD + c0 * 8);
                const uint4 k1 = *reinterpret_cast<const uint4*>(
                    kp + (size_t)(b * S_LEN + t0 + r1) * KV_DIM + g * DHEAD + c1 * 8);
                const uint4 v0 = *reinterpret_cast<const uint4*>(
                    vpT + (size_t)((b * NG + g) * DHEAD + r0) * S_LEN + t0 + c0 * 8);
                const uint4 v1 = *reinterpret_cast<const uint4*>(
                    vpT + (size_t)((b * NG + g) * DHEAD + r1) * S_LEN + t0 + c1 * 8);
                *reinterpret_cast<uint4*>((char*)Ks + r0 * 128 + ((c0 * 16) ^ ((r0 & 7) << 4))) = k0;
                *reinterpret_cast<uint4*>((char*)Ks + r1 * 128 + ((c1 * 16) ^ ((r1 & 7) << 4))) = k1;
                *reinterpret_cast<uint4*>((char*)Vs + r0 * 128 + ((c0 * 16) ^ ((r0 & 7) << 4))) = v0;
                *reinterpret_cast<uint4*>((char*)Vs + r1 * 128 + ((c1 * 16) ^ ((r1 & 7) << 4))) = v1;
            }
            __syncthreads();

            // ---- S^T = mfma(K, Q): col = m = l15, row = t = ti*16 + l4*4 + r ----
            f32x4 sa[2][4] = {};
#pragma unroll
            for (int ti = 0; ti < 4; ++ti) {
                if (t0 + ti * 16 > mmaxw) continue;   // fully masked for this wave
                const int trow = ti * 16 + l15;
#pragma unroll
                for (int ks = 0; ks < 2; ++ks) {
                    const bf16x8 kf = *reinterpret_cast<const bf16x8*>(
                        (char*)Ks + trow * 128 + ((ks * 64 + l4 * 16) ^ ((trow & 7) << 4)));
#pragma unroll
                    for (int mi = 0; mi < 2; ++mi)
                        sa[mi][ti] = __builtin_amdgcn_mfma_f32_16x16x32_bf16(kf, qf[mi][ks], sa[mi][ti], 0, 0, 0);
                }
            }

            // ---- online softmax (log2 domain), P -> LDS packed ----
#pragma unroll
            for (int mi = 0; mi < 2; ++mi) {
                const int mrow = w * 32 + mi * 16 + l15;
                const int m = s0 + mrow;
                const bool dg = (t0 + KVB - 1) > (s0 + w * 32 + mi * 16);
                float pv[16];
                float rmax = -1e30f;
#pragma unroll
                for (int ti = 0; ti < 4; ++ti)
#pragma unroll
                    for (int r = 0; r < 4; ++r) {
                        float v = sa[mi][ti][r] * SCL;
                        if (dg && (t0 + ti * 16 + l4 * 4 + r > m)) v = -1e30f;
                        pv[ti * 4 + r] = v;
                        rmax = fmaxf(rmax, v);
                    }
                rmax = fmaxf(rmax, __shfl_xor(rmax, 16, 64));
                rmax = fmaxf(rmax, __shfl_xor(rmax, 32, 64));
                const float mnew = fmaxf(mrun[mi], rmax);
                const float corr = __builtin_amdgcn_exp2f(mrun[mi] - mnew);
                float rs = 0.f;
#pragma unroll
                for (int u = 0; u < 16; ++u) {
                    const float p = __builtin_amdgcn_exp2f(pv[u] - mnew);
                    pv[u] = p;
                    rs += p;
                }
                rs += __shfl_xor(rs, 16, 64);
                rs += __shfl_xor(rs, 32, 64);
                mrun[mi] = mnew;
                lrun[mi] = lrun[mi] * corr + rs;
#pragma unroll
                for (int nj = 0; nj < 4; ++nj)
                    o[mi][nj] *= corr;
#pragma unroll
                for (int ti = 0; ti < 4; ++ti) {
                    uint2 pkv;
                    pkv.x = pk2(pv[ti * 4 + 0], pv[ti * 4 + 1]);
                    pkv.y = pk2(pv[ti * 4 + 2], pv[ti * 4 + 3]);
                    *reinterpret_cast<uint2*>(
                        (char*)Ps + mrow * 128 + ((ti * 32 + l4 * 8) ^ ((mrow & 7) << 4))) = pkv;
                }
            }
            __syncthreads();

            // ---- O^T += mfma(A=V(dh,t), B=P(m,t)): col = m = l15, row = dh ----
#pragma unroll
            for (int ks2 = 0; ks2 < 2; ++ks2) {
                if (t0 + ks2 * 32 > mmaxw) continue;  // P chunk all-zero for this wave
                bf16x8 pf[2];
#pragma unroll
                for (int mi = 0; mi < 2; ++mi) {
                    const int mrow = w * 32 + mi * 16 + l15;
                    pf[mi] = *reinterpret_cast<const bf16x8*>(
                        (char*)Ps + mrow * 128 + ((ks2 * 64 + l4 * 16) ^ ((mrow & 7) << 4)));
                }
#pragma unroll
                for (int nj = 0; nj < 4; ++nj) {
                    const int dr = nj * 16 + l15;
                    const bf16x8 vf = *reinterpret_cast<const bf16x8*>(
                        (char*)Vs + dr * 128 + ((ks2 * 64 + l4 * 16) ^ ((dr & 7) << 4)));
#pragma unroll
                    for (int mi = 0; mi < 2; ++mi)
                        o[mi][nj] = __builtin_amdgcn_mfma_f32_16x16x32_bf16(vf, pf[mi], o[mi][nj], 0, 0, 0);
                }
            }
            __syncthreads();
        }

        // ---- epilogue: normalize + packed store ----
#pragma unroll
        for (int mi = 0; mi < 2; ++mi) {
            const float inv = 1.0f / lrun[mi];
            const int srow = s0 + w * 32 + mi * 16 + l15;
#pragma unroll
            for (int nj = 0; nj < 4; ++nj) {
                uint2 pkv;
                pkv.x = pk2(o[mi][nj][0] * inv, o[mi][nj][1] * inv);
                pkv.y = pk2(o[mi][nj][2] * inv, o[mi][nj][3] * inv);
                *reinterpret_cast<uint2*>(
                    attn_out + (size_t)(b * S_LEN + srow) * D_MODEL + head * DHEAD + nj * 16 + l4 * 4) = pkv;
            }
        }
    }
}

// ---------------- host launch ----------------
extern "C" void kernel_launch(void* const* d_in, const int* in_sizes, int n_in,
                              void* d_out, int out_size, void* d_ws, size_t ws_size,
                              hipStream_t stream) {
    const float* q     = (const float*)d_in[0];
    const float* k     = (const float*)d_in[1];
    const float* v     = (const float*)d_in[2];
    // d_in[3] = causal mask, known analytically -> ignored
    const float* w_q   = (const float*)d_in[4];
    const float* w_k   = (const float*)d_in[5];
    const float* w_v   = (const float*)d_in[6];
    const float* w_out = (const float*)d_in[7];

    char* ws = (char*)d_ws;
    size_t off = 0;
    auto alloc = [&](size_t n) { char* p = ws + off; off += (n + 255) & ~(size_t)255; return p; };
    unsigned short* xb  = (unsigned short*)alloc((size_t)M_TOK * D_MODEL * 2);
    unsigned short* wb8 = (unsigned short*)alloc((size_t)D_MODEL * D_MODEL * 2);
    unsigned short* wkb = (unsigned short*)alloc((size_t)KV_DIM * D_MODEL * 2);
    unsigned short* wvb = (unsigned short*)alloc((size_t)KV_DIM * D_MODEL * 2);
    unsigned short* qpb = (unsigned short*)alloc((size_t)M_TOK * D_MODEL * 2);
    unsigned short* kpb = (unsigned short*)alloc((size_t)M_TOK * KV_DIM * 2);
    unsigned short* vpb = (unsigned short*)alloc((size_t)M_TOK * KV_DIM * 2);
    unsigned short* vtb = (unsigned short*)alloc((size_t)M_TOK * KV_DIM * 2);
    unsigned short* aob = (unsigned short*)alloc((size_t)M_TOK * D_MODEL * 2);
    unsigned int*   cnt = (unsigned int*)alloc(256);

    dim3 blk(256);
    int n8_qkv = M_TOK * D_MODEL / 8;
    int n8_wq  = D_MODEL * D_MODEL / 8;
    int n8_wkv = KV_DIM * D_MODEL / 8;

    cvt_kernel<<<dim3(n8_wq / 256), blk, 0, stream>>>(w_q, wb8, n8_wq);
    cvt_kernel<<<dim3(n8_wkv / 256), blk, 0, stream>>>(w_k, wkb, n8_wkv);
    cvt_kernel<<<dim3(n8_wkv / 256), blk, 0, stream>>>(w_v, wvb, n8_wkv);

    cvt_kernel<<<dim3(n8_qkv / 256), blk, 0, stream>>>(q, xb, n8_qkv);
    gemm_bt<0><<<dim3(M_TOK / 128, D_MODEL / 128), blk, 0, stream>>>(xb, wb8, qpb, M_TOK, D_MODEL, D_MODEL);
    cvt_kernel<<<dim3(n8_qkv / 256), blk, 0, stream>>>(k, xb, n8_qkv);
    gemm_bt<0><<<dim3(M_TOK / 128, KV_DIM / 128), blk, 0, stream>>>(xb, wkb, kpb, M_TOK, KV_DIM, D_MODEL);
    cvt_kernel<<<dim3(n8_qkv / 256), blk, 0, stream>>>(v, xb, n8_qkv);
    gemm_bt<0><<<dim3(M_TOK / 128, KV_DIM / 128), blk, 0, stream>>>(xb, wvb, vpb, M_TOK, KV_DIM, D_MODEL);

    cvt_kernel<<<dim3(n8_wq / 256), blk, 0, stream>>>(w_out, wb8, n8_wq);
    transpose_v<<<dim3(262144 / 256), blk, 0, stream>>>(vpb, vtb);

    init_counter<<<dim3(1), dim3(1), 0, stream>>>(cnt);
    attn_kernel<<<dim3(N_ITEMS), blk, 0, stream>>>(qpb, kpb, vtb, aob, cnt);

    gemm_bt<1><<<dim3(M_TOK / 128, D_MODEL / 128), blk, 0, stream>>>(aob, wb8, (float*)d_out, M_TOK, D_MODEL, D_MODEL);
}

// Round 3
// 292.225 us; speedup vs baseline: 2.2167x; 1.2329x over previous
//
#include <hip/hip_runtime.h>
#include <hip/hip_bf16.h>
#include <stdint.h>

#define B_SZ 2
#define S_LEN 2048
#define D_MODEL 2048
#define NH 32
#define NG 8
#define HGRP 4
#define DHEAD 64
#define KV_DIM 512       // NG*DHEAD
#define M_TOK 4096       // B_SZ*S_LEN
#define KVB 64           // attention KV tile
#define N_ITEMS 1536     // 24 slot-classes * 64 (b,head)

typedef __attribute__((ext_vector_type(8))) short bf16x8;
typedef __attribute__((ext_vector_type(4))) float f32x4;

__device__ inline unsigned short f2bf(float x) {
    uint32_t u = __builtin_bit_cast(uint32_t, x);
    uint32_t r = (u + 0x7fffu + ((u >> 16) & 1u)) >> 16;
    return (unsigned short)r;
}

__device__ inline uint32_t cvtpk(float lo, float hi) {
    uint32_t r;
    asm("v_cvt_pk_bf16_f32 %0, %1, %2" : "=v"(r) : "v"(lo), "v"(hi));
    return r;
}

__device__ inline float bf2f(unsigned short u) {
    uint32_t x = ((uint32_t)u) << 16;
    return __builtin_bit_cast(float, x);
}

__device__ inline void async_copy16(const void* g, void* l) {
    __builtin_amdgcn_global_load_lds(
        (const __attribute__((address_space(1))) void*)g,
        (__attribute__((address_space(3))) void*)l,
        16, 0, 0);
}

// ---------------- f32 -> bf16 converts ----------------
__global__ __launch_bounds__(256) void cvt_kernel(const float* __restrict__ in,
                                                  unsigned short* __restrict__ out,
                                                  int n8) {
    int i = blockIdx.x * 256 + threadIdx.x;
    if (i >= n8) return;
    const float4* p = reinterpret_cast<const float4*>(in) + (size_t)i * 2;
    float4 a = p[0], b = p[1];
    union { unsigned short u[8]; uint4 v; } r;
    r.u[0] = f2bf(a.x); r.u[1] = f2bf(a.y); r.u[2] = f2bf(a.z); r.u[3] = f2bf(a.w);
    r.u[4] = f2bf(b.x); r.u[5] = f2bf(b.y); r.u[6] = f2bf(b.z); r.u[7] = f2bf(b.w);
    reinterpret_cast<uint4*>(out)[i] = r.v;
}

// q,k,v in one launch (4096 blocks each); also zeroes the attn work counter.
__global__ __launch_bounds__(256) void cvt3_kernel(const float* __restrict__ q,
                                                   const float* __restrict__ k,
                                                   const float* __restrict__ v,
                                                   unsigned short* __restrict__ qo,
                                                   unsigned short* __restrict__ ko,
                                                   unsigned short* __restrict__ vo,
                                                   unsigned int* __restrict__ cnt) {
    int bid = blockIdx.x;
    if (bid == 0 && threadIdx.x == 0) *cnt = 0u;
    int which = bid >> 12;
    int i = (bid & 4095) * 256 + threadIdx.x;
    const float* src = (which == 0) ? q : (which == 1) ? k : v;
    unsigned short* dst = (which == 0) ? qo : (which == 1) ? ko : vo;
    const float4* p = reinterpret_cast<const float4*>(src) + (size_t)i * 2;
    float4 a = p[0], b = p[1];
    union { unsigned short u[8]; uint4 v4; } r;
    r.u[0] = f2bf(a.x); r.u[1] = f2bf(a.y); r.u[2] = f2bf(a.z); r.u[3] = f2bf(a.w);
    r.u[4] = f2bf(b.x); r.u[5] = f2bf(b.y); r.u[6] = f2bf(b.z); r.u[7] = f2bf(b.w);
    reinterpret_cast<uint4*>(dst)[i] = r.v4;
}

// ---------------- fused q/k/v projection ----------------
// blocks 0..511: q-proj (M=4096,N=2048), output pre-scaled by 0.125*log2(e).
// blocks 512..767: kv-proj (N=1024 = wk||wv); k half -> kpb [4096][512],
// v half -> vtb [B,G,DH,S] (transposed write, packed uint2).
#define SCALE_Q 0.1803368867f
__global__ __launch_bounds__(256) void proj_kernel(const unsigned short* __restrict__ qb,
                                                   const unsigned short* __restrict__ kb,
                                                   const unsigned short* __restrict__ vb,
                                                   const unsigned short* __restrict__ wq,
                                                   const unsigned short* __restrict__ wkv,
                                                   unsigned short* __restrict__ qpb,
                                                   unsigned short* __restrict__ kpb,
                                                   unsigned short* __restrict__ vtb) {
    __shared__ unsigned short As[128 * 32];
    __shared__ unsigned short Bs[128 * 32];
    const int tid = threadIdx.x;
    const int lane = tid & 63;
    const int w = tid >> 6;
    const int wr = w >> 1, wc = w & 1;
    const int l15 = lane & 15, l4 = lane >> 4;
    const int bid = blockIdx.x;

    const unsigned short *A, *Bw;
    int m0, n0, mode;
    if (bid < 512) { m0 = (bid >> 4) * 128; n0 = (bid & 15) * 128; A = qb; Bw = wq; mode = 0; }
    else {
        int c = bid - 512;
        m0 = (c >> 3) * 128; n0 = (c & 7) * 128; Bw = wkv;
        if (n0 < 512) { A = kb; mode = 1; } else { A = vb; mode = 2; }
    }
    const int K = D_MODEL;
    f32x4 acc[4][4] = {};

    for (int kt = 0; kt < K; kt += 32) {
#pragma unroll
        for (int j = 0; j < 2; ++j) {
            int c = j * 256 + tid;
            int row = c >> 2, col = (c & 3) * 8;
            async_copy16(A + (size_t)(m0 + row) * K + kt + col, &As[c * 8]);
        }
#pragma unroll
        for (int j = 0; j < 2; ++j) {
            int c = j * 256 + tid;
            int row = c >> 2, col = (c & 3) * 8;
            async_copy16(Bw + (size_t)(n0 + row) * K + kt + col, &Bs[c * 8]);
        }
        __syncthreads();
        bf16x8 af[4], bfr[4];
#pragma unroll
        for (int i = 0; i < 4; ++i) {
            af[i] = *reinterpret_cast<const bf16x8*>(&As[(wr * 64 + i * 16 + l15) * 32 + l4 * 8]);
            bfr[i] = *reinterpret_cast<const bf16x8*>(&Bs[(wc * 64 + i * 16 + l15) * 32 + l4 * 8]);
        }
#pragma unroll
        for (int i = 0; i < 4; ++i)
#pragma unroll
            for (int jn = 0; jn < 4; ++jn)
                acc[i][jn] = __builtin_amdgcn_mfma_f32_16x16x32_bf16(af[i], bfr[jn], acc[i][jn], 0, 0, 0);
        __syncthreads();
    }

    if (mode == 0) {
#pragma unroll
        for (int i = 0; i < 4; ++i) {
            int row = m0 + wr * 64 + i * 16 + l4 * 4;
#pragma unroll
            for (int jn = 0; jn < 4; ++jn) {
                int col = n0 + wc * 64 + jn * 16 + l15;
#pragma unroll
                for (int r = 0; r < 4; ++r)
                    qpb[(size_t)(row + r) * D_MODEL + col] = f2bf(acc[i][jn][r] * SCALE_Q);
            }
        }
    } else if (mode == 1) {
#pragma unroll
        for (int i = 0; i < 4; ++i) {
            int row = m0 + wr * 64 + i * 16 + l4 * 4;
#pragma unroll
            for (int jn = 0; jn < 4; ++jn) {
                int col = n0 + wc * 64 + jn * 16 + l15;
#pragma unroll
                for (int r = 0; r < 4; ++r)
                    kpb[(size_t)(row + r) * KV_DIM + col] = f2bf(acc[i][jn][r]);
            }
        }
    } else {
        const int bb = m0 >> 11;
        const int mb = m0 & 2047;
#pragma unroll
        for (int i = 0; i < 4; ++i) {
            int tok = mb + wr * 64 + i * 16 + l4 * 4;
#pragma unroll
            for (int jn = 0; jn < 4; ++jn) {
                int c = (n0 - 512) + wc * 64 + jn * 16 + l15;
                int g = c >> 6, dh = c & 63;
                uint2 pkv;
                pkv.x = cvtpk(acc[i][jn][0], acc[i][jn][1]);
                pkv.y = cvtpk(acc[i][jn][2], acc[i][jn][3]);
                *reinterpret_cast<uint2*>(
                    vtb + (size_t)((bb * NG + g) * DHEAD + dh) * S_LEN + tok) = pkv;
            }
        }
    }
}

// ---------------- output projection GEMM (f32 out) ----------------
__global__ __launch_bounds__(256) void gemm_out(const unsigned short* __restrict__ A,
                                                const unsigned short* __restrict__ Bm,
                                                float* __restrict__ Cout,
                                                int M, int N, int K) {
    __shared__ unsigned short As[128 * 32];
    __shared__ unsigned short Bs[128 * 32];
    int tid = threadIdx.x;
    int lane = tid & 63;
    int w = tid >> 6;
    int wr = w >> 1, wc = w & 1;
    int l15 = lane & 15, l4 = lane >> 4;
    int m0 = blockIdx.x * 128;
    int n0 = blockIdx.y * 128;
    f32x4 acc[4][4] = {};

    for (int kt = 0; kt < K; kt += 32) {
#pragma unroll
        for (int j = 0; j < 2; ++j) {
            int c = j * 256 + tid;
            int row = c >> 2, col = (c & 3) * 8;
            async_copy16(A + (size_t)(m0 + row) * K + kt + col, &As[c * 8]);
        }
#pragma unroll
        for (int j = 0; j < 2; ++j) {
            int c = j * 256 + tid;
            int row = c >> 2, col = (c & 3) * 8;
            async_copy16(Bm + (size_t)(n0 + row) * K + kt + col, &Bs[c * 8]);
        }
        __syncthreads();
        bf16x8 af[4], bfr[4];
#pragma unroll
        for (int i = 0; i < 4; ++i) {
            af[i] = *reinterpret_cast<const bf16x8*>(&As[(wr * 64 + i * 16 + l15) * 32 + l4 * 8]);
            bfr[i] = *reinterpret_cast<const bf16x8*>(&Bs[(wc * 64 + i * 16 + l15) * 32 + l4 * 8]);
        }
#pragma unroll
        for (int i = 0; i < 4; ++i)
#pragma unroll
            for (int jn = 0; jn < 4; ++jn)
                acc[i][jn] = __builtin_amdgcn_mfma_f32_16x16x32_bf16(af[i], bfr[jn], acc[i][jn], 0, 0, 0);
        __syncthreads();
    }
#pragma unroll
    for (int i = 0; i < 4; ++i) {
        int row = m0 + wr * 64 + i * 16 + l4 * 4;
#pragma unroll
        for (int jn = 0; jn < 4; ++jn) {
            int col = n0 + wc * 64 + jn * 16 + l15;
#pragma unroll
            for (int r = 0; r < 4; ++r)
                Cout[(size_t)(row + r) * N + col] = acc[i][jn][r];
        }
    }
}

// ---------------- flash attention v3 ----------------
// Work queue of 1536 items (heavy-first): qi<8 unsplit, qi>=8 split into two
// KV halves writing partial (m,l,O-bf16) merged by merge_kernel.
// Swapped QK^T; softmax in exp2 domain (scale folded into q-projection).
__constant__ unsigned char cls_qi[24]   = {7,15,15,14,14,6,13,13,12,12,5,11,11,10,10,4,9,9,8,8,3,2,1,0};
__constant__ unsigned char cls_half[24] = {0,0,1,0,1,0,0,1,0,1,0,0,1,0,1,0,0,1,0,1,0,0,0,0};

__global__ __launch_bounds__(256) void attn_kernel(const unsigned short* __restrict__ qp,
                                                   const unsigned short* __restrict__ kp,
                                                   const unsigned short* __restrict__ vpT,
                                                   unsigned short* __restrict__ attn_out,
                                                   unsigned int* __restrict__ counter,
                                                   unsigned short* __restrict__ partO,
                                                   float* __restrict__ ml) {
    __shared__ __align__(16) unsigned short Ks[KVB * 64];   // [t][dh] swz, 8KB
    __shared__ __align__(16) unsigned short Vs[64 * KVB];   // [dh][t] swz, 8KB
    __shared__ __align__(16) unsigned short Ps[128 * KVB];  // [m][t]  swz, 16KB
    __shared__ int s_item;

    const int tid = threadIdx.x;
    const int lane = tid & 63;
    const int w = tid >> 6;
    const int l15 = lane & 15, l4 = lane >> 4;

    for (;;) {
        if (tid == 0) s_item = (int)atomicAdd(counter, 1u);
        __syncthreads();
        const int item = s_item;
        if (item >= N_ITEMS) break;
        const int slot = item >> 6;
        const int bh = item & 63;
        const int qi = cls_qi[slot];
        const int half = cls_half[slot];
        const bool split = qi >= 8;
        const int b = bh >> 5, head = bh & 31, g = head >> 2;
        const int s0 = qi * 128;
        const int mmaxw = s0 + w * 32 + 31;

        int j0, j1;
        if (split) { j0 = half * (qi + 1); j1 = j0 + (qi + 1); }
        else       { j0 = 0;              j1 = 2 * (qi + 1); }

        bf16x8 qf[2][2];
#pragma unroll
        for (int mi = 0; mi < 2; ++mi)
#pragma unroll
            for (int ks = 0; ks < 2; ++ks)
                qf[mi][ks] = *reinterpret_cast<const bf16x8*>(
                    qp + (size_t)(b * S_LEN + s0 + w * 32 + mi * 16 + l15) * D_MODEL
                       + head * DHEAD + ks * 32 + l4 * 8);

        float mrun[2] = {-1e30f, -1e30f};
        float lrun[2] = {0.f, 0.f};
        f32x4 o[2][4] = {};

        for (int j = j0; j < j1; ++j) {
            const int t0 = j * KVB;

            // ---- stage K,V (reg-staged, XOR-swizzled rows) ----
            {
                const int r0 = tid >> 3, c0 = tid & 7;
                const int r1 = (tid + 256) >> 3;
                const uint4 k0 = *reinterpret_cast<const uint4*>(
                    kp + (size_t)(b * S_LEN + t0 + r0) * KV_DIM + g * DHEAD + c0 * 8);
                const uint4 k1 = *reinterpret_cast<const uint4*>(
                    kp + (size_t)(b * S_LEN + t0 + r1) * KV_DIM + g * DHEAD + c0 * 8);
                const uint4 v0 = *reinterpret_cast<const uint4*>(
                    vpT + (size_t)((b * NG + g) * DHEAD + r0) * S_LEN + t0 + c0 * 8);
                const uint4 v1 = *reinterpret_cast<const uint4*>(
                    vpT + (size_t)((b * NG + g) * DHEAD + r1) * S_LEN + t0 + c0 * 8);
                *reinterpret_cast<uint4*>((char*)Ks + r0 * 128 + ((c0 * 16) ^ ((r0 & 7) << 4))) = k0;
                *reinterpret_cast<uint4*>((char*)Ks + r1 * 128 + ((c0 * 16) ^ ((r1 & 7) << 4))) = k1;
                *reinterpret_cast<uint4*>((char*)Vs + r0 * 128 + ((c0 * 16) ^ ((r0 & 7) << 4))) = v0;
                *reinterpret_cast<uint4*>((char*)Vs + r1 * 128 + ((c0 * 16) ^ ((r1 & 7) << 4))) = v1;
            }
            __syncthreads();

            // ---- S^T = mfma(K, Q) ----
            f32x4 sa[2][4] = {};
#pragma unroll
            for (int ti = 0; ti < 4; ++ti) {
                if (t0 + ti * 16 > mmaxw) continue;
                const int trow = ti * 16 + l15;
#pragma unroll
                for (int ks = 0; ks < 2; ++ks) {
                    const bf16x8 kf = *reinterpret_cast<const bf16x8*>(
                        (char*)Ks + trow * 128 + ((ks * 64 + l4 * 16) ^ ((trow & 7) << 4)));
#pragma unroll
                    for (int mi = 0; mi < 2; ++mi)
                        sa[mi][ti] = __builtin_amdgcn_mfma_f32_16x16x32_bf16(kf, qf[mi][ks], sa[mi][ti], 0, 0, 0);
                }
            }

            // ---- online softmax ----
#pragma unroll
            for (int mi = 0; mi < 2; ++mi) {
                const int mrow = w * 32 + mi * 16 + l15;
                const int m = s0 + mrow;
                float pv[16];
                float rmax = -1e30f;
                if (t0 + KVB - 1 > s0 + w * 32 + mi * 16) {   // masked tile
#pragma unroll
                    for (int ti = 0; ti < 4; ++ti)
#pragma unroll
                        for (int r = 0; r < 4; ++r) {
                            float v = sa[mi][ti][r];
                            if (t0 + ti * 16 + l4 * 4 + r > m) v = -1e30f;
                            pv[ti * 4 + r] = v;
                            rmax = fmaxf(rmax, v);
                        }
                } else {                                       // unmasked
#pragma unroll
                    for (int ti = 0; ti < 4; ++ti)
#pragma unroll
                        for (int r = 0; r < 4; ++r) {
                            float v = sa[mi][ti][r];
                            pv[ti * 4 + r] = v;
                            rmax = fmaxf(rmax, v);
                        }
                }
                rmax = fmaxf(rmax, __shfl_xor(rmax, 16, 64));
                rmax = fmaxf(rmax, __shfl_xor(rmax, 32, 64));
                float mnew = mrun[mi];
                if (!__all(rmax <= mrun[mi] + 8.0f)) {         // T13 defer-max
                    mnew = fmaxf(mrun[mi], rmax);
                    const float corr = __builtin_amdgcn_exp2f(mrun[mi] - mnew);
                    lrun[mi] *= corr;
#pragma unroll
                    for (int nj = 0; nj < 4; ++nj)
                        o[mi][nj] *= corr;
                    mrun[mi] = mnew;
                }
                float rs = 0.f;
#pragma unroll
                for (int u = 0; u < 16; ++u) {
                    const float p = __builtin_amdgcn_exp2f(pv[u] - mnew);
                    pv[u] = p;
                    rs += p;
                }
                rs += __shfl_xor(rs, 16, 64);
                rs += __shfl_xor(rs, 32, 64);
                lrun[mi] += rs;
#pragma unroll
                for (int ti = 0; ti < 4; ++ti) {
                    uint2 pkv;
                    pkv.x = cvtpk(pv[ti * 4 + 0], pv[ti * 4 + 1]);
                    pkv.y = cvtpk(pv[ti * 4 + 2], pv[ti * 4 + 3]);
                    *reinterpret_cast<uint2*>(
                        (char*)Ps + mrow * 128 + ((ti * 32 + l4 * 8) ^ ((mrow & 7) << 4))) = pkv;
                }
            }
            __syncthreads();

            // ---- O^T += mfma(V, P) ----
#pragma unroll
            for (int ks2 = 0; ks2 < 2; ++ks2) {
                if (t0 + ks2 * 32 > mmaxw) continue;
                bf16x8 pf[2];
#pragma unroll
                for (int mi = 0; mi < 2; ++mi) {
                    const int mrow = w * 32 + mi * 16 + l15;
                    pf[mi] = *reinterpret_cast<const bf16x8*>(
                        (char*)Ps + mrow * 128 + ((ks2 * 64 + l4 * 16) ^ ((mrow & 7) << 4)));
                }
#pragma unroll
                for (int nj = 0; nj < 4; ++nj) {
                    const int dr = nj * 16 + l15;
                    const bf16x8 vf = *reinterpret_cast<const bf16x8*>(
                        (char*)Vs + dr * 128 + ((ks2 * 64 + l4 * 16) ^ ((dr & 7) << 4)));
#pragma unroll
                    for (int mi = 0; mi < 2; ++mi)
                        o[mi][nj] = __builtin_amdgcn_mfma_f32_16x16x32_bf16(vf, pf[mi], o[mi][nj], 0, 0, 0);
                }
            }
            __syncthreads();
        }

        if (split) {
            const int pb = ((bh << 3) + (qi - 8)) * 2 + half;
#pragma unroll
            for (int mi = 0; mi < 2; ++mi) {
                const int mrow = w * 32 + mi * 16 + l15;
                if (l4 == 0) {
                    ml[pb * 256 + mrow] = mrun[mi];
                    ml[pb * 256 + 128 + mrow] = lrun[mi];
                }
#pragma unroll
                for (int nj = 0; nj < 4; ++nj) {
                    uint2 pkv;
                    pkv.x = cvtpk(o[mi][nj][0], o[mi][nj][1]);
                    pkv.y = cvtpk(o[mi][nj][2], o[mi][nj][3]);
                    *reinterpret_cast<uint2*>(
                        partO + (size_t)pb * 8192 + mrow * 64 + nj * 16 + l4 * 4) = pkv;
                }
            }
        } else {
#pragma unroll
            for (int mi = 0; mi < 2; ++mi) {
                const float inv = 1.0f / lrun[mi];
                const int srow = s0 + w * 32 + mi * 16 + l15;
#pragma unroll
                for (int nj = 0; nj < 4; ++nj) {
                    uint2 pkv;
                    pkv.x = cvtpk(o[mi][nj][0] * inv, o[mi][nj][1] * inv);
                    pkv.y = cvtpk(o[mi][nj][2] * inv, o[mi][nj][3] * inv);
                    *reinterpret_cast<uint2*>(
                        attn_out + (size_t)(b * S_LEN + srow) * D_MODEL + head * DHEAD + nj * 16 + l4 * 4) = pkv;
                }
            }
        }
    }
}

// ---------------- merge two KV-halves ----------------
__global__ __launch_bounds__(256) void merge_kernel(const unsigned short* __restrict__ partO,
                                                    const float* __restrict__ ml,
                                                    unsigned short* __restrict__ attn_out) {
    const int blk = blockIdx.x;          // bh*8 + (qi-8)
    const int bh = blk >> 3;
    const int qi = (blk & 7) + 8;
    const int b = bh >> 5, head = bh & 31;
    const int s0 = qi * 128;
    const int tid = threadIdx.x;
    const int row = tid >> 1, dh0 = (tid & 1) * 32;
    const int pb0 = blk * 2, pb1 = pb0 + 1;

    const float m0 = ml[pb0 * 256 + row], l0 = ml[pb0 * 256 + 128 + row];
    const float m1 = ml[pb1 * 256 + row], l1 = ml[pb1 * 256 + 128 + row];
    const float M = fmaxf(m0, m1);
    float w0 = __builtin_amdgcn_exp2f(m0 - M);
    float w1 = __builtin_amdgcn_exp2f(m1 - M);
    const float inv = 1.0f / (l0 * w0 + l1 * w1);
    w0 *= inv; w1 *= inv;

    const uint4* p0 = reinterpret_cast<const uint4*>(partO + (size_t)pb0 * 8192 + row * 64 + dh0);
    const uint4* p1 = reinterpret_cast<const uint4*>(partO + (size_t)pb1 * 8192 + row * 64 + dh0);
    unsigned short* dst = attn_out + (size_t)(b * S_LEN + s0 + row) * D_MODEL + head * DHEAD + dh0;
#pragma unroll
    for (int c = 0; c < 4; ++c) {
        union { unsigned short u[8]; uint4 v; } ua, ub, uo;
        ua.v = p0[c]; ub.v = p1[c];
#pragma unroll
        for (int e = 0; e < 8; e += 2) {
            float x0 = bf2f(ua.u[e]) * w0 + bf2f(ub.u[e]) * w1;
            float x1 = bf2f(ua.u[e + 1]) * w0 + bf2f(ub.u[e + 1]) * w1;
            reinterpret_cast<uint32_t*>(uo.u)[e >> 1] = cvtpk(x0, x1);
        }
        reinterpret_cast<uint4*>(dst)[c] = uo.v;
    }
}

// ---------------- host launch ----------------
extern "C" void kernel_launch(void* const* d_in, const int* in_sizes, int n_in,
                              void* d_out, int out_size, void* d_ws, size_t ws_size,
                              hipStream_t stream) {
    const float* q     = (const float*)d_in[0];
    const float* k     = (const float*)d_in[1];
    const float* v     = (const float*)d_in[2];
    const float* w_q   = (const float*)d_in[4];
    const float* w_k   = (const float*)d_in[5];
    const float* w_v   = (const float*)d_in[6];
    const float* w_out = (const float*)d_in[7];

    char* ws = (char*)d_ws;
    size_t off = 0;
    auto alloc = [&](size_t n) { char* p = ws + off; off += (n + 255) & ~(size_t)255; return p; };
    unsigned short* qb   = (unsigned short*)alloc((size_t)M_TOK * D_MODEL * 2);   // also partO after proj
    unsigned short* kb   = (unsigned short*)alloc((size_t)M_TOK * D_MODEL * 2);
    unsigned short* vb   = (unsigned short*)alloc((size_t)M_TOK * D_MODEL * 2);
    unsigned short* wqb  = (unsigned short*)alloc((size_t)D_MODEL * D_MODEL * 2);
    unsigned short* wkvb = (unsigned short*)alloc((size_t)2 * KV_DIM * D_MODEL * 2);
    unsigned short* wob  = (unsigned short*)alloc((size_t)D_MODEL * D_MODEL * 2);
    unsigned short* qpb  = (unsigned short*)alloc((size_t)M_TOK * D_MODEL * 2);
    unsigned short* kpb  = (unsigned short*)alloc((size_t)M_TOK * KV_DIM * 2);
    unsigned short* vtb  = (unsigned short*)alloc((size_t)M_TOK * KV_DIM * 2);
    unsigned short* aob  = (unsigned short*)alloc((size_t)M_TOK * D_MODEL * 2);
    float*          mlb  = (float*)alloc((size_t)1024 * 256 * 4);
    unsigned int*   cnt  = (unsigned int*)alloc(256);

    dim3 blk(256);
    int n8_wq  = D_MODEL * D_MODEL / 8;
    int n8_wkv = KV_DIM * D_MODEL / 8;

    // converts (q,k,v fused; counter reset inside)
    cvt3_kernel<<<dim3(3 * 4096), blk, 0, stream>>>(q, k, v, qb, kb, vb, cnt);
    cvt_kernel<<<dim3(n8_wq / 256), blk, 0, stream>>>(w_q, wqb, n8_wq);
    cvt_kernel<<<dim3(n8_wkv / 256), blk, 0, stream>>>(w_k, wkvb, n8_wkv);
    cvt_kernel<<<dim3(n8_wkv / 256), blk, 0, stream>>>(w_v, wkvb + (size_t)KV_DIM * D_MODEL, n8_wkv);
    cvt_kernel<<<dim3(n8_wq / 256), blk, 0, stream>>>(w_out, wob, n8_wq);

    // fused projections (q scaled; v written transposed)
    proj_kernel<<<dim3(768), blk, 0, stream>>>(qb, kb, vb, wqb, wkvb, qpb, kpb, vtb);

    // attention (partO reuses qb)
    attn_kernel<<<dim3(1024), blk, 0, stream>>>(qpb, kpb, vtb, aob, cnt, qb, mlb);
    merge_kernel<<<dim3(512), blk, 0, stream>>>(qb, mlb, aob);

    // output projection
    gemm_out<<<dim3(M_TOK / 128, D_MODEL / 128), blk, 0, stream>>>(aob, wob, (float*)d_out, M_TOK, D_MODEL, D_MODEL);
}

// Round 4
// 249.011 us; speedup vs baseline: 2.6014x; 1.1735x over previous
//
#include <hip/hip_runtime.h>
#include <hip/hip_bf16.h>
#include <stdint.h>

#define B_SZ 2
#define S_LEN 2048
#define D_MODEL 2048
#define NH 32
#define NG 8
#define HGRP 4
#define DHEAD 64
#define KV_DIM 512       // NG*DHEAD
#define M_TOK 4096       // B_SZ*S_LEN
#define KVB 64           // attention KV tile
#define N_ITEMS 1536     // 24 slot-classes * 64 (b,head)

typedef __attribute__((ext_vector_type(8))) short bf16x8;
typedef __attribute__((ext_vector_type(4))) float f32x4;

__device__ inline unsigned short f2bf(float x) {
    uint32_t u = __builtin_bit_cast(uint32_t, x);
    uint32_t r = (u + 0x7fffu + ((u >> 16) & 1u)) >> 16;
    return (unsigned short)r;
}

__device__ inline uint32_t cvtpk(float lo, float hi) {
    uint32_t r;
    asm("v_cvt_pk_bf16_f32 %0, %1, %2" : "=v"(r) : "v"(lo), "v"(hi));
    return r;
}

__device__ inline float bf2f(unsigned short u) {
    uint32_t x = ((uint32_t)u) << 16;
    return __builtin_bit_cast(float, x);
}

__device__ inline void async_copy16(const void* g, void* l) {
    __builtin_amdgcn_global_load_lds(
        (const __attribute__((address_space(1))) void*)g,
        (__attribute__((address_space(3))) void*)l,
        16, 0, 0);
}

__device__ inline void gbar() {
    asm volatile("" ::: "memory");
    __builtin_amdgcn_s_barrier();
    asm volatile("" ::: "memory");
}
__device__ inline void lgkm0() {
    asm volatile("s_waitcnt lgkmcnt(0)" ::: "memory");
    __builtin_amdgcn_sched_barrier(0);
}

// ---------------- f32 -> bf16 converts ----------------
__global__ __launch_bounds__(256) void cvt_kernel(const float* __restrict__ in,
                                                  unsigned short* __restrict__ out,
                                                  int n8) {
    int i = blockIdx.x * 256 + threadIdx.x;
    if (i >= n8) return;
    const float4* p = reinterpret_cast<const float4*>(in) + (size_t)i * 2;
    float4 a = p[0], b = p[1];
    union { unsigned short u[8]; uint4 v; } r;
    r.u[0] = f2bf(a.x); r.u[1] = f2bf(a.y); r.u[2] = f2bf(a.z); r.u[3] = f2bf(a.w);
    r.u[4] = f2bf(b.x); r.u[5] = f2bf(b.y); r.u[6] = f2bf(b.z); r.u[7] = f2bf(b.w);
    reinterpret_cast<uint4*>(out)[i] = r.v;
}

__global__ __launch_bounds__(256) void cvt3_kernel(const float* __restrict__ q,
                                                   const float* __restrict__ k,
                                                   const float* __restrict__ v,
                                                   unsigned short* __restrict__ qo,
                                                   unsigned short* __restrict__ ko,
                                                   unsigned short* __restrict__ vo,
                                                   unsigned int* __restrict__ cnt) {
    int bid = blockIdx.x;
    if (bid == 0 && threadIdx.x == 0) *cnt = 0u;
    int which = bid >> 12;
    int i = (bid & 4095) * 256 + threadIdx.x;
    const float* src = (which == 0) ? q : (which == 1) ? k : v;
    unsigned short* dst = (which == 0) ? qo : (which == 1) ? ko : vo;
    const float4* p = reinterpret_cast<const float4*>(src) + (size_t)i * 2;
    float4 a = p[0], b = p[1];
    union { unsigned short u[8]; uint4 v4; } r;
    r.u[0] = f2bf(a.x); r.u[1] = f2bf(a.y); r.u[2] = f2bf(a.z); r.u[3] = f2bf(a.w);
    r.u[4] = f2bf(b.x); r.u[5] = f2bf(b.y); r.u[6] = f2bf(b.z); r.u[7] = f2bf(b.w);
    reinterpret_cast<uint4*>(dst)[i] = r.v4;
}

// ---------------- 256x256 8-phase GEMM (C = A[M][K] * B[N][K]^T) ----------------
// 8 waves (2M x 4N), BK=64, 128KB LDS double-buffered, XOR-swizzle
// (byte ^= (row&7)<<4) via pre-swizzled global source + swizzled ds_read.
// Counted vmcnt(4) at phases 4 & 8; drains only in last iteration.
// WHICH=0: fused projections, N-stacked [wq(2048) | wk(512) | wv(512)].
// WHICH=1: out-projection, f32 output.
#define SCALE_Q 0.1803368867f   // 0.125 * log2(e)
#define GK 2048
#define NTILES 32               // GK/64

template<int WHICH>
__global__ __launch_bounds__(512, 2) void gemm8(const unsigned short* __restrict__ Aq,
                                                const unsigned short* __restrict__ Ak,
                                                const unsigned short* __restrict__ Av,
                                                const unsigned short* __restrict__ Bq,
                                                const unsigned short* __restrict__ Bkv,
                                                unsigned short* __restrict__ out_q,
                                                unsigned short* __restrict__ out_k,
                                                unsigned short* __restrict__ out_v,
                                                float* __restrict__ out_f) {
    __shared__ __align__(16) char lds[131072];   // A: [0,64K) = buf0|buf1, B: [64K,128K)

    const int tid = threadIdx.x;
    const int lane = tid & 63;
    const int w = tid >> 6;
    const int wm = w >> 2, wn = w & 3;
    const int l15 = lane & 15, l4 = lane >> 4;

    // XCD-aware bijective swizzle (grid % 8 == 0)
    const int nblk = (WHICH == 0) ? 192 : 128;
    int bid = blockIdx.x;
    bid = (bid & 7) * (nblk >> 3) + (bid >> 3);
    const int mb = bid & 15, nb = bid >> 4;
    const int m0 = mb * 256;

    const unsigned short* Ap;
    const unsigned short* Bp;
    int mode = 0, n0q = 0;
    if (WHICH == 1) {
        Ap = Aq; Bp = Bq + (size_t)(nb * 256) * GK; n0q = nb * 256;
    } else if (nb < 8) {
        Ap = Aq; Bp = Bq + (size_t)(nb * 256) * GK; mode = 0; n0q = nb * 256;
    } else if (nb < 10) {
        Ap = Ak; Bp = Bkv + (size_t)((nb - 8) * 256) * GK; mode = 1; n0q = (nb - 8) * 256;
    } else {
        Ap = Av; Bp = Bkv + (size_t)((nb - 10) * 256 + 512) * GK; mode = 2; n0q = (nb - 10) * 256;
    }

    // staging geometry: thread covers 16B at (row = tid>>3 [+64], colb = (tid&7)*16)
    const int srow = tid >> 3;
    const int gcol = (((tid & 7) * 16) ^ ((srow & 7) << 4)) >> 1;  // inverse-swizzled src col
    char* const myl = lds + tid * 16;

    auto stageA = [&](int tile, int half) {
        char* dst = myl + (tile & 1) * 32768 + half * 16384;
        const unsigned short* src = Ap + (size_t)(m0 + half * 128 + srow) * GK + tile * 64 + gcol;
        async_copy16(src, dst);
        async_copy16(src + (size_t)64 * GK, dst + 8192);
    };
    auto stageB = [&](int tile, int half) {
        char* dst = myl + 65536 + (tile & 1) * 32768 + half * 16384;
        const unsigned short* src = Bp + (size_t)(half * 128 + srow) * GK + tile * 64 + gcol;
        async_copy16(src, dst);
        async_copy16(src + (size_t)64 * GK, dst + 8192);
    };

    bf16x8 af[4][2], bf[4][2];
    auto loadA = [&](int buf, int mhalf) {       // af[0..3] rows wm*128 + mhalf*64 + mi*16 + l15
        const char* base = lds + buf * 32768;
#pragma unroll
        for (int mi = 0; mi < 4; ++mi) {
            const int r = wm * 128 + mhalf * 64 + mi * 16 + l15;
#pragma unroll
            for (int ks = 0; ks < 2; ++ks)
                af[mi][ks] = *reinterpret_cast<const bf16x8*>(
                    base + r * 128 + ((ks * 64 + l4 * 16) ^ ((r & 7) << 4)));
        }
    };
    auto loadB = [&](int buf, int nhalf) {       // bf[nhalf*2 .. +1] rows wn*64 + ni*16 + l15
        const char* base = lds + 65536 + buf * 32768;
#pragma unroll
        for (int ni2 = 0; ni2 < 2; ++ni2) {
            const int ni = nhalf * 2 + ni2;
            const int r = wn * 64 + ni * 16 + l15;
#pragma unroll
            for (int ks = 0; ks < 2; ++ks)
                bf[ni][ks] = *reinterpret_cast<const bf16x8*>(
                    base + r * 128 + ((ks * 64 + l4 * 16) ^ ((r & 7) << 4)));
        }
    };

    f32x4 acc[8][4] = {};
    auto mfma16 = [&](int mq, int nq) {
        __builtin_amdgcn_s_setprio(1);
#pragma unroll
        for (int mi = 0; mi < 4; ++mi)
#pragma unroll
            for (int ni2 = 0; ni2 < 2; ++ni2)
#pragma unroll
                for (int ks = 0; ks < 2; ++ks)
                    acc[mq * 4 + mi][nq * 2 + ni2] = __builtin_amdgcn_mfma_f32_16x16x32_bf16(
                        af[mi][ks], bf[nq * 2 + ni2][ks], acc[mq * 4 + mi][nq * 2 + ni2], 0, 0, 0);
        __builtin_amdgcn_s_setprio(0);
    };

    // prologue: tile0 all 4 halves + tile1 B halves; land tile0 (oldest 8 of 12)
    stageA(0, 0); stageA(0, 1); stageB(0, 0); stageB(0, 1); stageB(1, 0); stageB(1, 1);
    asm volatile("s_waitcnt vmcnt(4)" ::: "memory");
    gbar();

    for (int i = 0; i < 16; ++i) {
        const int u = 2 * i;
        const bool nl = (i < 15);
        // ---------- tile u (buf 0) ----------
        loadA(0, 0); loadB(0, 0); stageA(u + 1, 0);
        gbar(); lgkm0(); mfma16(0, 0); gbar();
        loadB(0, 1); stageA(u + 1, 1);
        gbar(); lgkm0(); mfma16(0, 1); gbar();
        loadA(0, 1); if (nl) stageB(u + 2, 0);
        gbar(); lgkm0(); mfma16(1, 0); gbar();
        if (nl) stageB(u + 2, 1);
        gbar(); mfma16(1, 1);
        if (nl) asm volatile("s_waitcnt vmcnt(4)" ::: "memory");
        else    asm volatile("s_waitcnt vmcnt(0)" ::: "memory");
        gbar();
        // ---------- tile u+1 (buf 1) ----------
        loadA(1, 0); loadB(1, 0); if (nl) stageA(u + 2, 0);
        gbar(); lgkm0(); mfma16(0, 0); gbar();
        loadB(1, 1); if (nl) stageA(u + 2, 1);
        gbar(); lgkm0(); mfma16(0, 1); gbar();
        loadA(1, 1); if (nl) stageB(u + 3, 0);
        gbar(); lgkm0(); mfma16(1, 0); gbar();
        if (nl) stageB(u + 3, 1);
        gbar(); mfma16(1, 1);
        if (nl) asm volatile("s_waitcnt vmcnt(4)" ::: "memory");
        gbar();
    }

    // ---------------- epilogue ----------------
    if (WHICH == 1) {
#pragma unroll
        for (int mi = 0; mi < 8; ++mi) {
            const int row = m0 + wm * 128 + mi * 16 + l4 * 4;
#pragma unroll
            for (int ni = 0; ni < 4; ++ni) {
                const int col = n0q + wn * 64 + ni * 16 + l15;
#pragma unroll
                for (int r = 0; r < 4; ++r)
                    out_f[(size_t)(row + r) * D_MODEL + col] = acc[mi][ni][r];
            }
        }
    } else if (mode == 0) {
#pragma unroll
        for (int mi = 0; mi < 8; ++mi) {
            const int row = m0 + wm * 128 + mi * 16 + l4 * 4;
#pragma unroll
            for (int ni = 0; ni < 4; ++ni) {
                const int col = n0q + wn * 64 + ni * 16 + l15;
#pragma unroll
                for (int r = 0; r < 4; ++r)
                    out_q[(size_t)(row + r) * D_MODEL + col] = f2bf(acc[mi][ni][r] * SCALE_Q);
            }
        }
    } else if (mode == 1) {
#pragma unroll
        for (int mi = 0; mi < 8; ++mi) {
            const int row = m0 + wm * 128 + mi * 16 + l4 * 4;
#pragma unroll
            for (int ni = 0; ni < 4; ++ni) {
                const int col = n0q + wn * 64 + ni * 16 + l15;
#pragma unroll
                for (int r = 0; r < 4; ++r)
                    out_k[(size_t)(row + r) * KV_DIM + col] = f2bf(acc[mi][ni][r]);
            }
        }
    } else {
        const int bb = m0 >> 11;
#pragma unroll
        for (int mi = 0; mi < 8; ++mi) {
            const int tok = (m0 & 2047) + wm * 128 + mi * 16 + l4 * 4;
#pragma unroll
            for (int ni = 0; ni < 4; ++ni) {
                const int c = n0q + wn * 64 + ni * 16 + l15;
                const int g = c >> 6, dh = c & 63;
                uint2 pk;
                pk.x = cvtpk(acc[mi][ni][0], acc[mi][ni][1]);
                pk.y = cvtpk(acc[mi][ni][2], acc[mi][ni][3]);
                *reinterpret_cast<uint2*>(out_v + (size_t)((bb * NG + g) * DHEAD + dh) * S_LEN + tok) = pk;
            }
        }
    }
}

// ---------------- flash attention (unchanged from round 3) ----------------
__constant__ unsigned char cls_qi[24]   = {7,15,15,14,14,6,13,13,12,12,5,11,11,10,10,4,9,9,8,8,3,2,1,0};
__constant__ unsigned char cls_half[24] = {0,0,1,0,1,0,0,1,0,1,0,0,1,0,1,0,0,1,0,1,0,0,0,0};

__global__ __launch_bounds__(256) void attn_kernel(const unsigned short* __restrict__ qp,
                                                   const unsigned short* __restrict__ kp,
                                                   const unsigned short* __restrict__ vpT,
                                                   unsigned short* __restrict__ attn_out,
                                                   unsigned int* __restrict__ counter,
                                                   unsigned short* __restrict__ partO,
                                                   float* __restrict__ ml) {
    __shared__ __align__(16) unsigned short Ks[KVB * 64];
    __shared__ __align__(16) unsigned short Vs[64 * KVB];
    __shared__ __align__(16) unsigned short Ps[128 * KVB];
    __shared__ int s_item;

    const int tid = threadIdx.x;
    const int lane = tid & 63;
    const int w = tid >> 6;
    const int l15 = lane & 15, l4 = lane >> 4;

    for (;;) {
        if (tid == 0) s_item = (int)atomicAdd(counter, 1u);
        __syncthreads();
        const int item = s_item;
        if (item >= N_ITEMS) break;
        const int slot = item >> 6;
        const int bh = item & 63;
        const int qi = cls_qi[slot];
        const int half = cls_half[slot];
        const bool split = qi >= 8;
        const int b = bh >> 5, head = bh & 31, g = head >> 2;
        const int s0 = qi * 128;
        const int mmaxw = s0 + w * 32 + 31;

        int j0, j1;
        if (split) { j0 = half * (qi + 1); j1 = j0 + (qi + 1); }
        else       { j0 = 0;              j1 = 2 * (qi + 1); }

        bf16x8 qf[2][2];
#pragma unroll
        for (int mi = 0; mi < 2; ++mi)
#pragma unroll
            for (int ks = 0; ks < 2; ++ks)
                qf[mi][ks] = *reinterpret_cast<const bf16x8*>(
                    qp + (size_t)(b * S_LEN + s0 + w * 32 + mi * 16 + l15) * D_MODEL
                       + head * DHEAD + ks * 32 + l4 * 8);

        float mrun[2] = {-1e30f, -1e30f};
        float lrun[2] = {0.f, 0.f};
        f32x4 o[2][4] = {};

        for (int j = j0; j < j1; ++j) {
            const int t0 = j * KVB;
            {
                const int r0 = tid >> 3, c0 = tid & 7;
                const int r1 = (tid + 256) >> 3;
                const uint4 k0 = *reinterpret_cast<const uint4*>(
                    kp + (size_t)(b * S_LEN + t0 + r0) * KV_DIM + g * DHEAD + c0 * 8);
                const uint4 k1 = *reinterpret_cast<const uint4*>(
                    kp + (size_t)(b * S_LEN + t0 + r1) * KV_DIM + g * DHEAD + c0 * 8);
                const uint4 v0 = *reinterpret_cast<const uint4*>(
                    vpT + (size_t)((b * NG + g) * DHEAD + r0) * S_LEN + t0 + c0 * 8);
                const uint4 v1 = *reinterpret_cast<const uint4*>(
                    vpT + (size_t)((b * NG + g) * DHEAD + r1) * S_LEN + t0 + c0 * 8);
                *reinterpret_cast<uint4*>((char*)Ks + r0 * 128 + ((c0 * 16) ^ ((r0 & 7) << 4))) = k0;
                *reinterpret_cast<uint4*>((char*)Ks + r1 * 128 + ((c0 * 16) ^ ((r1 & 7) << 4))) = k1;
                *reinterpret_cast<uint4*>((char*)Vs + r0 * 128 + ((c0 * 16) ^ ((r0 & 7) << 4))) = v0;
                *reinterpret_cast<uint4*>((char*)Vs + r1 * 128 + ((c0 * 16) ^ ((r1 & 7) << 4))) = v1;
            }
            __syncthreads();

            f32x4 sa[2][4] = {};
#pragma unroll
            for (int ti = 0; ti < 4; ++ti) {
                if (t0 + ti * 16 > mmaxw) continue;
                const int trow = ti * 16 + l15;
#pragma unroll
                for (int ks = 0; ks < 2; ++ks) {
                    const bf16x8 kf = *reinterpret_cast<const bf16x8*>(
                        (char*)Ks + trow * 128 + ((ks * 64 + l4 * 16) ^ ((trow & 7) << 4)));
#pragma unroll
                    for (int mi = 0; mi < 2; ++mi)
                        sa[mi][ti] = __builtin_amdgcn_mfma_f32_16x16x32_bf16(kf, qf[mi][ks], sa[mi][ti], 0, 0, 0);
                }
            }

#pragma unroll
            for (int mi = 0; mi < 2; ++mi) {
                const int mrow = w * 32 + mi * 16 + l15;
                const int m = s0 + mrow;
                float pv[16];
                float rmax = -1e30f;
                if (t0 + KVB - 1 > s0 + w * 32 + mi * 16) {
#pragma unroll
                    for (int ti = 0; ti < 4; ++ti)
#pragma unroll
                        for (int r = 0; r < 4; ++r) {
                            float v = sa[mi][ti][r];
                            if (t0 + ti * 16 + l4 * 4 + r > m) v = -1e30f;
                            pv[ti * 4 + r] = v;
                            rmax = fmaxf(rmax, v);
                        }
                } else {
#pragma unroll
                    for (int ti = 0; ti < 4; ++ti)
#pragma unroll
                        for (int r = 0; r < 4; ++r) {
                            float v = sa[mi][ti][r];
                            pv[ti * 4 + r] = v;
                            rmax = fmaxf(rmax, v);
                        }
                }
                rmax = fmaxf(rmax, __shfl_xor(rmax, 16, 64));
                rmax = fmaxf(rmax, __shfl_xor(rmax, 32, 64));
                float mnew = mrun[mi];
                if (!__all(rmax <= mrun[mi] + 8.0f)) {
                    mnew = fmaxf(mrun[mi], rmax);
                    const float corr = __builtin_amdgcn_exp2f(mrun[mi] - mnew);
                    lrun[mi] *= corr;
#pragma unroll
                    for (int nj = 0; nj < 4; ++nj)
                        o[mi][nj] *= corr;
                    mrun[mi] = mnew;
                }
                float rs = 0.f;
#pragma unroll
                for (int u = 0; u < 16; ++u) {
                    const float p = __builtin_amdgcn_exp2f(pv[u] - mnew);
                    pv[u] = p;
                    rs += p;
                }
                rs += __shfl_xor(rs, 16, 64);
                rs += __shfl_xor(rs, 32, 64);
                lrun[mi] += rs;
#pragma unroll
                for (int ti = 0; ti < 4; ++ti) {
                    uint2 pkv;
                    pkv.x = cvtpk(pv[ti * 4 + 0], pv[ti * 4 + 1]);
                    pkv.y = cvtpk(pv[ti * 4 + 2], pv[ti * 4 + 3]);
                    *reinterpret_cast<uint2*>(
                        (char*)Ps + mrow * 128 + ((ti * 32 + l4 * 8) ^ ((mrow & 7) << 4))) = pkv;
                }
            }
            __syncthreads();

#pragma unroll
            for (int ks2 = 0; ks2 < 2; ++ks2) {
                if (t0 + ks2 * 32 > mmaxw) continue;
                bf16x8 pf[2];
#pragma unroll
                for (int mi = 0; mi < 2; ++mi) {
                    const int mrow = w * 32 + mi * 16 + l15;
                    pf[mi] = *reinterpret_cast<const bf16x8*>(
                        (char*)Ps + mrow * 128 + ((ks2 * 64 + l4 * 16) ^ ((mrow & 7) << 4)));
                }
#pragma unroll
                for (int nj = 0; nj < 4; ++nj) {
                    const int dr = nj * 16 + l15;
                    const bf16x8 vf = *reinterpret_cast<const bf16x8*>(
                        (char*)Vs + dr * 128 + ((ks2 * 64 + l4 * 16) ^ ((dr & 7) << 4)));
#pragma unroll
                    for (int mi = 0; mi < 2; ++mi)
                        o[mi][nj] = __builtin_amdgcn_mfma_f32_16x16x32_bf16(vf, pf[mi], o[mi][nj], 0, 0, 0);
                }
            }
            __syncthreads();
        }

        if (split) {
            const int pb = ((bh << 3) + (qi - 8)) * 2 + half;
#pragma unroll
            for (int mi = 0; mi < 2; ++mi) {
                const int mrow = w * 32 + mi * 16 + l15;
                if (l4 == 0) {
                    ml[pb * 256 + mrow] = mrun[mi];
                    ml[pb * 256 + 128 + mrow] = lrun[mi];
                }
#pragma unroll
                for (int nj = 0; nj < 4; ++nj) {
                    uint2 pkv;
                    pkv.x = cvtpk(o[mi][nj][0], o[mi][nj][1]);
                    pkv.y = cvtpk(o[mi][nj][2], o[mi][nj][3]);
                    *reinterpret_cast<uint2*>(
                        partO + (size_t)pb * 8192 + mrow * 64 + nj * 16 + l4 * 4) = pkv;
                }
            }
        } else {
#pragma unroll
            for (int mi = 0; mi < 2; ++mi) {
                const float inv = 1.0f / lrun[mi];
                const int srow = s0 + w * 32 + mi * 16 + l15;
#pragma unroll
                for (int nj = 0; nj < 4; ++nj) {
                    uint2 pkv;
                    pkv.x = cvtpk(o[mi][nj][0] * inv, o[mi][nj][1] * inv);
                    pkv.y = cvtpk(o[mi][nj][2] * inv, o[mi][nj][3] * inv);
                    *reinterpret_cast<uint2*>(
                        attn_out + (size_t)(b * S_LEN + srow) * D_MODEL + head * DHEAD + nj * 16 + l4 * 4) = pkv;
                }
            }
        }
    }
}

// ---------------- merge two KV-halves ----------------
__global__ __launch_bounds__(256) void merge_kernel(const unsigned short* __restrict__ partO,
                                                    const float* __restrict__ ml,
                                                    unsigned short* __restrict__ attn_out) {
    const int blk = blockIdx.x;
    const int bh = blk >> 3;
    const int qi = (blk & 7) + 8;
    const int b = bh >> 5, head = bh & 31;
    const int s0 = qi * 128;
    const int tid = threadIdx.x;
    const int row = tid >> 1, dh0 = (tid & 1) * 32;
    const int pb0 = blk * 2, pb1 = pb0 + 1;

    const float m0 = ml[pb0 * 256 + row], l0 = ml[pb0 * 256 + 128 + row];
    const float m1 = ml[pb1 * 256 + row], l1 = ml[pb1 * 256 + 128 + row];
    const float M = fmaxf(m0, m1);
    float w0 = __builtin_amdgcn_exp2f(m0 - M);
    float w1 = __builtin_amdgcn_exp2f(m1 - M);
    const float inv = 1.0f / (l0 * w0 + l1 * w1);
    w0 *= inv; w1 *= inv;

    const uint4* p0 = reinterpret_cast<const uint4*>(partO + (size_t)pb0 * 8192 + row * 64 + dh0);
    const uint4* p1 = reinterpret_cast<const uint4*>(partO + (size_t)pb1 * 8192 + row * 64 + dh0);
    unsigned short* dst = attn_out + (size_t)(b * S_LEN + s0 + row) * D_MODEL + head * DHEAD + dh0;
#pragma unroll
    for (int c = 0; c < 4; ++c) {
        union { unsigned short u[8]; uint4 v; } ua, ub, uo;
        ua.v = p0[c]; ub.v = p1[c];
#pragma unroll
        for (int e = 0; e < 8; e += 2) {
            float x0 = bf2f(ua.u[e]) * w0 + bf2f(ub.u[e]) * w1;
            float x1 = bf2f(ua.u[e + 1]) * w0 + bf2f(ub.u[e + 1]) * w1;
            reinterpret_cast<uint32_t*>(uo.u)[e >> 1] = cvtpk(x0, x1);
        }
        reinterpret_cast<uint4*>(dst)[c] = uo.v;
    }
}

// ---------------- host launch ----------------
extern "C" void kernel_launch(void* const* d_in, const int* in_sizes, int n_in,
                              void* d_out, int out_size, void* d_ws, size_t ws_size,
                              hipStream_t stream) {
    const float* q     = (const float*)d_in[0];
    const float* k     = (const float*)d_in[1];
    const float* v     = (const float*)d_in[2];
    const float* w_q   = (const float*)d_in[4];
    const float* w_k   = (const float*)d_in[5];
    const float* w_v   = (const float*)d_in[6];
    const float* w_out = (const float*)d_in[7];

    char* ws = (char*)d_ws;
    size_t off = 0;
    auto alloc = [&](size_t n) { char* p = ws + off; off += (n + 255) & ~(size_t)255; return p; };
    unsigned short* qb   = (unsigned short*)alloc((size_t)M_TOK * D_MODEL * 2);  // partO after proj
    unsigned short* kb   = (unsigned short*)alloc((size_t)M_TOK * D_MODEL * 2);
    unsigned short* vb   = (unsigned short*)alloc((size_t)M_TOK * D_MODEL * 2);
    unsigned short* wqb  = (unsigned short*)alloc((size_t)D_MODEL * D_MODEL * 2);
    unsigned short* wkvb = (unsigned short*)alloc((size_t)2 * KV_DIM * D_MODEL * 2);
    unsigned short* wob  = (unsigned short*)alloc((size_t)D_MODEL * D_MODEL * 2);
    unsigned short* qpb  = (unsigned short*)alloc((size_t)M_TOK * D_MODEL * 2);
    unsigned short* kpb  = (unsigned short*)alloc((size_t)M_TOK * KV_DIM * 2);
    unsigned short* vtb  = (unsigned short*)alloc((size_t)M_TOK * KV_DIM * 2);
    unsigned short* aob  = (unsigned short*)alloc((size_t)M_TOK * D_MODEL * 2);
    float*          mlb  = (float*)alloc((size_t)1024 * 256 * 4);
    unsigned int*   cnt  = (unsigned int*)alloc(256);

    dim3 blk(256);
    int n8_wq  = D_MODEL * D_MODEL / 8;
    int n8_wkv = KV_DIM * D_MODEL / 8;

    cvt3_kernel<<<dim3(3 * 4096), blk, 0, stream>>>(q, k, v, qb, kb, vb, cnt);
    cvt_kernel<<<dim3(n8_wq / 256), blk, 0, stream>>>(w_q, wqb, n8_wq);
    cvt_kernel<<<dim3(n8_wkv / 256), blk, 0, stream>>>(w_k, wkvb, n8_wkv);
    cvt_kernel<<<dim3(n8_wkv / 256), blk, 0, stream>>>(w_v, wkvb + (size_t)KV_DIM * D_MODEL, n8_wkv);
    cvt_kernel<<<dim3(n8_wq / 256), blk, 0, stream>>>(w_out, wob, n8_wq);

    // fused q/k/v projections: 192 blocks (q:128, k:32, v:32), 8-phase 256^2
    gemm8<0><<<dim3(192), dim3(512), 0, stream>>>(qb, kb, vb, wqb, wkvb, qpb, kpb, vtb, nullptr);

    attn_kernel<<<dim3(1024), blk, 0, stream>>>(qpb, kpb, vtb, aob, cnt, qb, mlb);
    merge_kernel<<<dim3(512), blk, 0, stream>>>(qb, mlb, aob);

    // output projection: 128 blocks, f32 out
    gemm8<1><<<dim3(128), dim3(512), 0, stream>>>(aob, nullptr, nullptr, wob, nullptr,
                                                  nullptr, nullptr, nullptr, (float*)d_out);
}

// Round 5
// 240.191 us; speedup vs baseline: 2.6969x; 1.0367x over previous
//
#include <hip/hip_runtime.h>
#include <hip/hip_bf16.h>
#include <stdint.h>

#define B_SZ 2
#define S_LEN 2048
#define D_MODEL 2048
#define NH 32
#define NG 8
#define HGRP 4
#define DHEAD 64
#define KV_DIM 512       // NG*DHEAD
#define M_TOK 4096       // B_SZ*S_LEN
#define KVB 64           // attention KV tile
#define QBLK 256
#define N_ITEMS2 768     // 12 slot-classes * 64 (b,head)

typedef __attribute__((ext_vector_type(8))) short bf16x8;
typedef __attribute__((ext_vector_type(4))) float f32x4;

__device__ inline unsigned short f2bf(float x) {
    uint32_t u = __builtin_bit_cast(uint32_t, x);
    uint32_t r = (u + 0x7fffu + ((u >> 16) & 1u)) >> 16;
    return (unsigned short)r;
}

__device__ inline uint32_t cvtpk(float lo, float hi) {
    uint32_t r;
    asm("v_cvt_pk_bf16_f32 %0, %1, %2" : "=v"(r) : "v"(lo), "v"(hi));
    return r;
}

__device__ inline float bf2f(unsigned short u) {
    uint32_t x = ((uint32_t)u) << 16;
    return __builtin_bit_cast(float, x);
}

__device__ inline void async_copy16(const void* g, void* l) {
    __builtin_amdgcn_global_load_lds(
        (const __attribute__((address_space(1))) void*)g,
        (__attribute__((address_space(3))) void*)l,
        16, 0, 0);
}

__device__ inline void gbar() {
    asm volatile("" ::: "memory");
    __builtin_amdgcn_s_barrier();
    asm volatile("" ::: "memory");
}
__device__ inline void lgkm0() {
    asm volatile("s_waitcnt lgkmcnt(0)" ::: "memory");
    __builtin_amdgcn_sched_barrier(0);
}

// ---------------- fused f32 -> bf16 convert (all 7 tensors) ----------------
// n8-chunk ranges (all multiples of 256 so branches are block-uniform):
// q[0,1048576) k[..2097152) v[..3145728) wq[..3670016) wk[..3801088)
// wv[..3932160) wo[..4456448)
__global__ __launch_bounds__(256) void cvt_all(const float* __restrict__ q,
                                               const float* __restrict__ k,
                                               const float* __restrict__ v,
                                               const float* __restrict__ wq,
                                               const float* __restrict__ wk,
                                               const float* __restrict__ wv,
                                               const float* __restrict__ wo,
                                               unsigned short* __restrict__ qb,
                                               unsigned short* __restrict__ kb,
                                               unsigned short* __restrict__ vb,
                                               unsigned short* __restrict__ wqb,
                                               unsigned short* __restrict__ wkvb,
                                               unsigned short* __restrict__ wob,
                                               unsigned int* __restrict__ cnt) {
    const int i = blockIdx.x * 256 + threadIdx.x;
    if (i == 0) *cnt = 0u;
    const float* src; unsigned short* dst; int j;
    if (i < 1048576)      { src = q;  dst = qb;  j = i; }
    else if (i < 2097152) { src = k;  dst = kb;  j = i - 1048576; }
    else if (i < 3145728) { src = v;  dst = vb;  j = i - 2097152; }
    else if (i < 3670016) { src = wq; dst = wqb; j = i - 3145728; }
    else if (i < 3801088) { src = wk; dst = wkvb; j = i - 3670016; }
    else if (i < 3932160) { src = wv; dst = wkvb + (size_t)KV_DIM * D_MODEL; j = i - 3801088; }
    else                  { src = wo; dst = wob; j = i - 3932160; }
    const float4* p = reinterpret_cast<const float4*>(src) + (size_t)j * 2;
    float4 a = p[0], b = p[1];
    union { unsigned short u[8]; uint4 v4; } r;
    r.u[0] = f2bf(a.x); r.u[1] = f2bf(a.y); r.u[2] = f2bf(a.z); r.u[3] = f2bf(a.w);
    r.u[4] = f2bf(b.x); r.u[5] = f2bf(b.y); r.u[6] = f2bf(b.z); r.u[7] = f2bf(b.w);
    reinterpret_cast<uint4*>(dst)[j] = r.v4;
}

// ---------------- 256x256 8-phase GEMM (C = A[M][K] * B[N][K]^T) ----------------
#define SCALE_Q 0.1803368867f   // 0.125 * log2(e)
#define GK 2048

template<int WHICH>
__global__ __launch_bounds__(512, 2) void gemm8(const unsigned short* __restrict__ Aq,
                                                const unsigned short* __restrict__ Ak,
                                                const unsigned short* __restrict__ Av,
                                                const unsigned short* __restrict__ Bq,
                                                const unsigned short* __restrict__ Bkv,
                                                unsigned short* __restrict__ out_q,
                                                unsigned short* __restrict__ out_k,
                                                unsigned short* __restrict__ out_v,
                                                float* __restrict__ out_f) {
    __shared__ __align__(16) char lds[131072];

    const int tid = threadIdx.x;
    const int lane = tid & 63;
    const int w = tid >> 6;
    const int wm = w >> 2, wn = w & 3;
    const int l15 = lane & 15, l4 = lane >> 4;

    const int nblk = (WHICH == 0) ? 192 : 128;
    int bid = blockIdx.x;
    bid = (bid & 7) * (nblk >> 3) + (bid >> 3);
    const int mb = bid & 15, nb = bid >> 4;
    const int m0 = mb * 256;

    const unsigned short* Ap;
    const unsigned short* Bp;
    int mode = 0, n0q = 0;
    if (WHICH == 1) {
        Ap = Aq; Bp = Bq + (size_t)(nb * 256) * GK; n0q = nb * 256;
    } else if (nb < 8) {
        Ap = Aq; Bp = Bq + (size_t)(nb * 256) * GK; mode = 0; n0q = nb * 256;
    } else if (nb < 10) {
        Ap = Ak; Bp = Bkv + (size_t)((nb - 8) * 256) * GK; mode = 1; n0q = (nb - 8) * 256;
    } else {
        Ap = Av; Bp = Bkv + (size_t)((nb - 10) * 256 + 512) * GK; mode = 2; n0q = (nb - 10) * 256;
    }

    const int srow = tid >> 3;
    const int gcol = (((tid & 7) * 16) ^ ((srow & 7) << 4)) >> 1;
    char* const myl = lds + tid * 16;

    auto stageA = [&](int tile, int half) {
        char* dst = myl + (tile & 1) * 32768 + half * 16384;
        const unsigned short* src = Ap + (size_t)(m0 + half * 128 + srow) * GK + tile * 64 + gcol;
        async_copy16(src, dst);
        async_copy16(src + (size_t)64 * GK, dst + 8192);
    };
    auto stageB = [&](int tile, int half) {
        char* dst = myl + 65536 + (tile & 1) * 32768 + half * 16384;
        const unsigned short* src = Bp + (size_t)(half * 128 + srow) * GK + tile * 64 + gcol;
        async_copy16(src, dst);
        async_copy16(src + (size_t)64 * GK, dst + 8192);
    };

    bf16x8 af[4][2], bf[4][2];
    auto loadA = [&](int buf, int mhalf) {
        const char* base = lds + buf * 32768;
#pragma unroll
        for (int mi = 0; mi < 4; ++mi) {
            const int r = wm * 128 + mhalf * 64 + mi * 16 + l15;
#pragma unroll
            for (int ks = 0; ks < 2; ++ks)
                af[mi][ks] = *reinterpret_cast<const bf16x8*>(
                    base + r * 128 + ((ks * 64 + l4 * 16) ^ ((r & 7) << 4)));
        }
    };
    auto loadB = [&](int buf, int nhalf) {
        const char* base = lds + 65536 + buf * 32768;
#pragma unroll
        for (int ni2 = 0; ni2 < 2; ++ni2) {
            const int ni = nhalf * 2 + ni2;
            const int r = wn * 64 + ni * 16 + l15;
#pragma unroll
            for (int ks = 0; ks < 2; ++ks)
                bf[ni][ks] = *reinterpret_cast<const bf16x8*>(
                    base + r * 128 + ((ks * 64 + l4 * 16) ^ ((r & 7) << 4)));
        }
    };

    f32x4 acc[8][4] = {};
    auto mfma16 = [&](int mq, int nq) {
        __builtin_amdgcn_s_setprio(1);
#pragma unroll
        for (int mi = 0; mi < 4; ++mi)
#pragma unroll
            for (int ni2 = 0; ni2 < 2; ++ni2)
#pragma unroll
                for (int ks = 0; ks < 2; ++ks)
                    acc[mq * 4 + mi][nq * 2 + ni2] = __builtin_amdgcn_mfma_f32_16x16x32_bf16(
                        af[mi][ks], bf[nq * 2 + ni2][ks], acc[mq * 4 + mi][nq * 2 + ni2], 0, 0, 0);
        __builtin_amdgcn_s_setprio(0);
    };

    stageA(0, 0); stageA(0, 1); stageB(0, 0); stageB(0, 1); stageB(1, 0); stageB(1, 1);
    asm volatile("s_waitcnt vmcnt(4)" ::: "memory");
    gbar();

    for (int i = 0; i < 16; ++i) {
        const int u = 2 * i;
        const bool nl = (i < 15);
        loadA(0, 0); loadB(0, 0); stageA(u + 1, 0);
        gbar(); lgkm0(); mfma16(0, 0); gbar();
        loadB(0, 1); stageA(u + 1, 1);
        gbar(); lgkm0(); mfma16(0, 1); gbar();
        loadA(0, 1); if (nl) stageB(u + 2, 0);
        gbar(); lgkm0(); mfma16(1, 0); gbar();
        if (nl) stageB(u + 2, 1);
        gbar(); mfma16(1, 1);
        if (nl) asm volatile("s_waitcnt vmcnt(4)" ::: "memory");
        else    asm volatile("s_waitcnt vmcnt(0)" ::: "memory");
        gbar();
        loadA(1, 0); loadB(1, 0); if (nl) stageA(u + 2, 0);
        gbar(); lgkm0(); mfma16(0, 0); gbar();
        loadB(1, 1); if (nl) stageA(u + 2, 1);
        gbar(); lgkm0(); mfma16(0, 1); gbar();
        loadA(1, 1); if (nl) stageB(u + 3, 0);
        gbar(); lgkm0(); mfma16(1, 0); gbar();
        if (nl) stageB(u + 3, 1);
        gbar(); mfma16(1, 1);
        if (nl) asm volatile("s_waitcnt vmcnt(4)" ::: "memory");
        gbar();
    }

    if (WHICH == 1) {
#pragma unroll
        for (int mi = 0; mi < 8; ++mi) {
            const int row = m0 + wm * 128 + mi * 16 + l4 * 4;
#pragma unroll
            for (int ni = 0; ni < 4; ++ni) {
                const int col = n0q + wn * 64 + ni * 16 + l15;
#pragma unroll
                for (int r = 0; r < 4; ++r)
                    out_f[(size_t)(row + r) * D_MODEL + col] = acc[mi][ni][r];
            }
        }
    } else if (mode == 0) {
#pragma unroll
        for (int mi = 0; mi < 8; ++mi) {
            const int row = m0 + wm * 128 + mi * 16 + l4 * 4;
#pragma unroll
            for (int ni = 0; ni < 4; ++ni) {
                const int col = n0q + wn * 64 + ni * 16 + l15;
#pragma unroll
                for (int r = 0; r < 4; ++r)
                    out_q[(size_t)(row + r) * D_MODEL + col] = f2bf(acc[mi][ni][r] * SCALE_Q);
            }
        }
    } else if (mode == 1) {
#pragma unroll
        for (int mi = 0; mi < 8; ++mi) {
            const int row = m0 + wm * 128 + mi * 16 + l4 * 4;
#pragma unroll
            for (int ni = 0; ni < 4; ++ni) {
                const int col = n0q + wn * 64 + ni * 16 + l15;
#pragma unroll
                for (int r = 0; r < 4; ++r)
                    out_k[(size_t)(row + r) * KV_DIM + col] = f2bf(acc[mi][ni][r]);
            }
        }
    } else {
        const int bb = m0 >> 11;
#pragma unroll
        for (int mi = 0; mi < 8; ++mi) {
            const int tok = (m0 & 2047) + wm * 128 + mi * 16 + l4 * 4;
#pragma unroll
            for (int ni = 0; ni < 4; ++ni) {
                const int c = n0q + wn * 64 + ni * 16 + l15;
                const int g = c >> 6, dh = c & 63;
                uint2 pk;
                pk.x = cvtpk(acc[mi][ni][0], acc[mi][ni][1]);
                pk.y = cvtpk(acc[mi][ni][2], acc[mi][ni][3]);
                *reinterpret_cast<uint2*>(out_v + (size_t)((bb * NG + g) * DHEAD + dh) * S_LEN + tok) = pk;
            }
        }
    }
}

// ---------------- flash attention v4: QBLK=256, 8 waves, K/V dbuf + prefetch ----
// 12 slot-classes heavy-first: qi>=4 split into two KV-halves (merged later).
__constant__ unsigned char cls2_qi[12]   = {7,7,3,6,6,5,5,2,4,4,1,0};
__constant__ unsigned char cls2_half[12] = {0,1,0,0,1,0,1,0,0,1,0,0};

__global__ __launch_bounds__(512) void attn2_kernel(const unsigned short* __restrict__ qp,
                                                    const unsigned short* __restrict__ kp,
                                                    const unsigned short* __restrict__ vpT,
                                                    unsigned short* __restrict__ attn_out,
                                                    unsigned int* __restrict__ counter,
                                                    unsigned short* __restrict__ partO,
                                                    float* __restrict__ ml) {
    __shared__ __align__(16) unsigned short Ks[2][KVB * 64];   // 8KB each, swz
    __shared__ __align__(16) unsigned short Vs[2][KVB * 64];   // 8KB each, swz
    __shared__ __align__(16) unsigned short Ps[QBLK * KVB];    // 32KB, swz
    __shared__ int s_item;

    const int tid = threadIdx.x;
    const int lane = tid & 63;
    const int w = tid >> 6;                 // 0..7
    const int l15 = lane & 15, l4 = lane >> 4;
    const int r0 = tid >> 3, c0 = tid & 7;  // staging: row 0..63, col-chunk 0..7
    const int sdst = r0 * 128 + ((c0 * 16) ^ ((r0 & 7) << 4));

    for (;;) {
        if (tid == 0) s_item = (int)atomicAdd(counter, 1u);
        __syncthreads();
        const int item = s_item;
        if (item >= N_ITEMS2) break;
        const int slot = item >> 6;
        const int bh = item & 63;
        const int qi = cls2_qi[slot];
        const int half = cls2_half[slot];
        const bool split = qi >= 4;
        const int b = bh >> 5, head = bh & 31, g = head >> 2;
        const int s0 = qi * QBLK;
        const int mmaxw = s0 + w * 32 + 31;

        int j0, j1;
        if (split) { j0 = half * 2 * (qi + 1); j1 = j0 + 2 * (qi + 1); }
        else       { j0 = 0;                   j1 = 4 * (qi + 1); }

        bf16x8 qf[2][2];
#pragma unroll
        for (int mi = 0; mi < 2; ++mi)
#pragma unroll
            for (int ks = 0; ks < 2; ++ks)
                qf[mi][ks] = *reinterpret_cast<const bf16x8*>(
                    qp + (size_t)(b * S_LEN + s0 + w * 32 + mi * 16 + l15) * D_MODEL
                       + head * DHEAD + ks * 32 + l4 * 8);

        float mrun[2] = {-1e30f, -1e30f};
        float lrun[2] = {0.f, 0.f};
        f32x4 o[2][4] = {};

        const unsigned short* kbase = kp + (size_t)(b * S_LEN + r0) * KV_DIM + g * DHEAD + c0 * 8;
        const unsigned short* vbase = vpT + (size_t)((b * NG + g) * DHEAD + r0) * S_LEN + c0 * 8;

        // prologue: stage tile j0 into buffer 0
        {
            const uint4 kr = *reinterpret_cast<const uint4*>(kbase + (size_t)j0 * KVB * KV_DIM);
            const uint4 vr = *reinterpret_cast<const uint4*>(vbase + j0 * KVB);
            *reinterpret_cast<uint4*>((char*)Ks[0] + sdst) = kr;
            *reinterpret_cast<uint4*>((char*)Vs[0] + sdst) = vr;
        }
        __syncthreads();

        for (int j = j0; j < j1; ++j) {
            const int cur = (j - j0) & 1;
            const int t0 = j * KVB;
            const bool pf = (j + 1 < j1);
            uint4 kr2, vr2;
            if (pf) {   // T14: issue next-tile loads early; wait lands at ds_write
                kr2 = *reinterpret_cast<const uint4*>(kbase + (size_t)(j + 1) * KVB * KV_DIM);
                vr2 = *reinterpret_cast<const uint4*>(vbase + (j + 1) * KVB);
            }

            // ---- S^T = mfma(K, Q) ----
            f32x4 sa[2][4] = {};
#pragma unroll
            for (int ti = 0; ti < 4; ++ti) {
                if (t0 + ti * 16 > mmaxw) continue;
                const int trow = ti * 16 + l15;
#pragma unroll
                for (int ks = 0; ks < 2; ++ks) {
                    const bf16x8 kf = *reinterpret_cast<const bf16x8*>(
                        (char*)Ks[cur] + trow * 128 + ((ks * 64 + l4 * 16) ^ ((trow & 7) << 4)));
#pragma unroll
                    for (int mi = 0; mi < 2; ++mi)
                        sa[mi][ti] = __builtin_amdgcn_mfma_f32_16x16x32_bf16(kf, qf[mi][ks], sa[mi][ti], 0, 0, 0);
                }
            }

            // ---- online softmax (exp2 domain; scale folded into q-proj) ----
#pragma unroll
            for (int mi = 0; mi < 2; ++mi) {
                const int mrow = w * 32 + mi * 16 + l15;
                const int m = s0 + mrow;
                float pv[16];
                float rmax = -1e30f;
                if (t0 + KVB - 1 > s0 + w * 32 + mi * 16) {
#pragma unroll
                    for (int ti = 0; ti < 4; ++ti)
#pragma unroll
                        for (int r = 0; r < 4; ++r) {
                            float v = sa[mi][ti][r];
                            if (t0 + ti * 16 + l4 * 4 + r > m) v = -1e30f;
                            pv[ti * 4 + r] = v;
                            rmax = fmaxf(rmax, v);
                        }
                } else {
#pragma unroll
                    for (int ti = 0; ti < 4; ++ti)
#pragma unroll
                        for (int r = 0; r < 4; ++r) {
                            float v = sa[mi][ti][r];
                            pv[ti * 4 + r] = v;
                            rmax = fmaxf(rmax, v);
                        }
                }
                rmax = fmaxf(rmax, __shfl_xor(rmax, 16, 64));
                rmax = fmaxf(rmax, __shfl_xor(rmax, 32, 64));
                float mnew = mrun[mi];
                if (!__all(rmax <= mrun[mi] + 8.0f)) {   // T13 defer-max
                    mnew = fmaxf(mrun[mi], rmax);
                    const float corr = __builtin_amdgcn_exp2f(mrun[mi] - mnew);
                    lrun[mi] *= corr;
#pragma unroll
                    for (int nj = 0; nj < 4; ++nj)
                        o[mi][nj] *= corr;
                    mrun[mi] = mnew;
                }
                float rs = 0.f;
#pragma unroll
                for (int u = 0; u < 16; ++u) {
                    const float p = __builtin_amdgcn_exp2f(pv[u] - mnew);
                    pv[u] = p;
                    rs += p;
                }
                rs += __shfl_xor(rs, 16, 64);
                rs += __shfl_xor(rs, 32, 64);
                lrun[mi] += rs;
#pragma unroll
                for (int ti = 0; ti < 4; ++ti) {
                    uint2 pkv;
                    pkv.x = cvtpk(pv[ti * 4 + 0], pv[ti * 4 + 1]);
                    pkv.y = cvtpk(pv[ti * 4 + 2], pv[ti * 4 + 3]);
                    *reinterpret_cast<uint2*>(
                        (char*)Ps + mrow * 128 + ((ti * 32 + l4 * 8) ^ ((mrow & 7) << 4))) = pkv;
                }
            }
            __syncthreads();   // Ps ready

            // ---- O^T += mfma(V, P) ----
#pragma unroll
            for (int ks2 = 0; ks2 < 2; ++ks2) {
                if (t0 + ks2 * 32 > mmaxw) continue;
                bf16x8 pf2[2];
#pragma unroll
                for (int mi = 0; mi < 2; ++mi) {
                    const int mrow = w * 32 + mi * 16 + l15;
                    pf2[mi] = *reinterpret_cast<const bf16x8*>(
                        (char*)Ps + mrow * 128 + ((ks2 * 64 + l4 * 16) ^ ((mrow & 7) << 4)));
                }
#pragma unroll
                for (int nj = 0; nj < 4; ++nj) {
                    const int dr = nj * 16 + l15;
                    const bf16x8 vf = *reinterpret_cast<const bf16x8*>(
                        (char*)Vs[cur] + dr * 128 + ((ks2 * 64 + l4 * 16) ^ ((dr & 7) << 4)));
#pragma unroll
                    for (int mi = 0; mi < 2; ++mi)
                        o[mi][nj] = __builtin_amdgcn_mfma_f32_16x16x32_bf16(vf, pf2[mi], o[mi][nj], 0, 0, 0);
                }
            }
            if (pf) {   // write prefetched tile into the other buffer
                *reinterpret_cast<uint4*>((char*)Ks[cur ^ 1] + sdst) = kr2;
                *reinterpret_cast<uint4*>((char*)Vs[cur ^ 1] + sdst) = vr2;
            }
            __syncthreads();   // next buffer ready; Ps reads done
        }

        if (split) {
            const int pb = ((bh << 2) + (qi - 4)) * 2 + half;
#pragma unroll
            for (int mi = 0; mi < 2; ++mi) {
                const int mrow = w * 32 + mi * 16 + l15;
                if (l4 == 0) {
                    ml[pb * 512 + mrow] = mrun[mi];
                    ml[pb * 512 + 256 + mrow] = lrun[mi];
                }
#pragma unroll
                for (int nj = 0; nj < 4; ++nj) {
                    uint2 pkv;
                    pkv.x = cvtpk(o[mi][nj][0], o[mi][nj][1]);
                    pkv.y = cvtpk(o[mi][nj][2], o[mi][nj][3]);
                    *reinterpret_cast<uint2*>(
                        partO + (size_t)pb * 16384 + mrow * 64 + nj * 16 + l4 * 4) = pkv;
                }
            }
        } else {
#pragma unroll
            for (int mi = 0; mi < 2; ++mi) {
                const float inv = 1.0f / lrun[mi];
                const int srow = s0 + w * 32 + mi * 16 + l15;
#pragma unroll
                for (int nj = 0; nj < 4; ++nj) {
                    uint2 pkv;
                    pkv.x = cvtpk(o[mi][nj][0] * inv, o[mi][nj][1] * inv);
                    pkv.y = cvtpk(o[mi][nj][2] * inv, o[mi][nj][3] * inv);
                    *reinterpret_cast<uint2*>(
                        attn_out + (size_t)(b * S_LEN + srow) * D_MODEL + head * DHEAD + nj * 16 + l4 * 4) = pkv;
                }
            }
        }
    }
}

// ---------------- merge two KV-halves (qi>=4) ----------------
__global__ __launch_bounds__(512) void merge2_kernel(const unsigned short* __restrict__ partO,
                                                     const float* __restrict__ ml,
                                                     unsigned short* __restrict__ attn_out) {
    const int blk = blockIdx.x;          // bh*4 + (qi-4)
    const int bh = blk >> 2;
    const int qi = (blk & 3) + 4;
    const int b = bh >> 5, head = bh & 31;
    const int s0 = qi * QBLK;
    const int tid = threadIdx.x;
    const int row = tid >> 1, dh0 = (tid & 1) * 32;
    const int pb0 = blk * 2, pb1 = pb0 + 1;

    const float m0 = ml[pb0 * 512 + row], l0 = ml[pb0 * 512 + 256 + row];
    const float m1 = ml[pb1 * 512 + row], l1 = ml[pb1 * 512 + 256 + row];
    const float M = fmaxf(m0, m1);
    float w0 = __builtin_amdgcn_exp2f(m0 - M);
    float w1 = __builtin_amdgcn_exp2f(m1 - M);
    const float inv = 1.0f / (l0 * w0 + l1 * w1);
    w0 *= inv; w1 *= inv;

    const uint4* p0 = reinterpret_cast<const uint4*>(partO + (size_t)pb0 * 16384 + row * 64 + dh0);
    const uint4* p1 = reinterpret_cast<const uint4*>(partO + (size_t)pb1 * 16384 + row * 64 + dh0);
    unsigned short* dst = attn_out + (size_t)(b * S_LEN + s0 + row) * D_MODEL + head * DHEAD + dh0;
#pragma unroll
    for (int c = 0; c < 4; ++c) {
        union { unsigned short u[8]; uint4 v; } ua, ub, uo;
        ua.v = p0[c]; ub.v = p1[c];
#pragma unroll
        for (int e = 0; e < 8; e += 2) {
            float x0 = bf2f(ua.u[e]) * w0 + bf2f(ub.u[e]) * w1;
            float x1 = bf2f(ua.u[e + 1]) * w0 + bf2f(ub.u[e + 1]) * w1;
            reinterpret_cast<uint32_t*>(uo.u)[e >> 1] = cvtpk(x0, x1);
        }
        reinterpret_cast<uint4*>(dst)[c] = uo.v;
    }
}

// ---------------- host launch ----------------
extern "C" void kernel_launch(void* const* d_in, const int* in_sizes, int n_in,
                              void* d_out, int out_size, void* d_ws, size_t ws_size,
                              hipStream_t stream) {
    const float* q     = (const float*)d_in[0];
    const float* k     = (const float*)d_in[1];
    const float* v     = (const float*)d_in[2];
    const float* w_q   = (const float*)d_in[4];
    const float* w_k   = (const float*)d_in[5];
    const float* w_v   = (const float*)d_in[6];
    const float* w_out = (const float*)d_in[7];

    char* ws = (char*)d_ws;
    size_t off = 0;
    auto alloc = [&](size_t n) { char* p = ws + off; off += (n + 255) & ~(size_t)255; return p; };
    unsigned short* qb   = (unsigned short*)alloc((size_t)M_TOK * D_MODEL * 2);  // partO after proj
    unsigned short* kb   = (unsigned short*)alloc((size_t)M_TOK * D_MODEL * 2);
    unsigned short* vb   = (unsigned short*)alloc((size_t)M_TOK * D_MODEL * 2);
    unsigned short* wqb  = (unsigned short*)alloc((size_t)D_MODEL * D_MODEL * 2);
    unsigned short* wkvb = (unsigned short*)alloc((size_t)2 * KV_DIM * D_MODEL * 2);
    unsigned short* wob  = (unsigned short*)alloc((size_t)D_MODEL * D_MODEL * 2);
    unsigned short* qpb  = (unsigned short*)alloc((size_t)M_TOK * D_MODEL * 2);
    unsigned short* kpb  = (unsigned short*)alloc((size_t)M_TOK * KV_DIM * 2);
    unsigned short* vtb  = (unsigned short*)alloc((size_t)M_TOK * KV_DIM * 2);
    unsigned short* aob  = (unsigned short*)alloc((size_t)M_TOK * D_MODEL * 2);
    float*          mlb  = (float*)alloc((size_t)512 * 512 * 4);
    unsigned int*   cnt  = (unsigned int*)alloc(256);

    // single fused convert (also resets the attn work counter)
    cvt_all<<<dim3(17408), dim3(256), 0, stream>>>(q, k, v, w_q, w_k, w_v, w_out,
                                                   qb, kb, vb, wqb, wkvb, wob, cnt);

    // fused q/k/v projections: 192 blocks (q:128, k:32, v:32), 8-phase 256^2
    gemm8<0><<<dim3(192), dim3(512), 0, stream>>>(qb, kb, vb, wqb, wkvb, qpb, kpb, vtb, nullptr);

    // attention: 512 persistent blocks, 8 waves, QBLK=256 (partO reuses qb)
    attn2_kernel<<<dim3(512), dim3(512), 0, stream>>>(qpb, kpb, vtb, aob, cnt, qb, mlb);
    merge2_kernel<<<dim3(256), dim3(512), 0, stream>>>(qb, mlb, aob);

    // output projection: 128 blocks, f32 out
    gemm8<1><<<dim3(128), dim3(512), 0, stream>>>(aob, nullptr, nullptr, wob, nullptr,
                                                  nullptr, nullptr, nullptr, (float*)d_out);
}

// Round 6
// 212.288 us; speedup vs baseline: 3.0514x; 1.1314x over previous
//
#include <hip/hip_runtime.h>
#include <hip/hip_bf16.h>
#include <stdint.h>

#define B_SZ 2
#define S_LEN 2048
#define D_MODEL 2048
#define NH 32
#define NG 8
#define HGRP 4
#define DHEAD 64
#define KV_DIM 512       // NG*DHEAD
#define M_TOK 4096       // B_SZ*S_LEN
#define KVB 64           // attention KV tile
#define QBLK 256
#define N_ITEMS2 768     // 12 slot-classes * 64 (b,head)

typedef __attribute__((ext_vector_type(8))) short bf16x8;
typedef __attribute__((ext_vector_type(4))) float f32x4;
typedef __attribute__((ext_vector_type(16))) float f32x16;

__device__ inline unsigned short f2bf(float x) {
    uint32_t u = __builtin_bit_cast(uint32_t, x);
    uint32_t r = (u + 0x7fffu + ((u >> 16) & 1u)) >> 16;
    return (unsigned short)r;
}

__device__ inline uint32_t cvtpk(float lo, float hi) {
    uint32_t r;
    asm("v_cvt_pk_bf16_f32 %0, %1, %2" : "=v"(r) : "v"(lo), "v"(hi));
    return r;
}

__device__ inline void plswap(uint32_t& a, uint32_t& b) {
    asm volatile("v_permlane32_swap_b32 %0, %1" : "+v"(a), "+v"(b));
}

__device__ inline float bf2f(unsigned short u) {
    uint32_t x = ((uint32_t)u) << 16;
    return __builtin_bit_cast(float, x);
}

__device__ inline void async_copy16(const void* g, void* l) {
    __builtin_amdgcn_global_load_lds(
        (const __attribute__((address_space(1))) void*)g,
        (__attribute__((address_space(3))) void*)l,
        16, 0, 0);
}

__device__ inline void gbar() {
    asm volatile("" ::: "memory");
    __builtin_amdgcn_s_barrier();
    asm volatile("" ::: "memory");
}
__device__ inline void lgkm0() {
    asm volatile("s_waitcnt lgkmcnt(0)" ::: "memory");
    __builtin_amdgcn_sched_barrier(0);
}

// ---------------- fused f32 -> bf16 convert (all 7 tensors) ----------------
__global__ __launch_bounds__(256) void cvt_all(const float* __restrict__ q,
                                               const float* __restrict__ k,
                                               const float* __restrict__ v,
                                               const float* __restrict__ wq,
                                               const float* __restrict__ wk,
                                               const float* __restrict__ wv,
                                               const float* __restrict__ wo,
                                               unsigned short* __restrict__ qb,
                                               unsigned short* __restrict__ kb,
                                               unsigned short* __restrict__ vb,
                                               unsigned short* __restrict__ wqb,
                                               unsigned short* __restrict__ wkvb,
                                               unsigned short* __restrict__ wob,
                                               unsigned int* __restrict__ cnt) {
    const int i = blockIdx.x * 256 + threadIdx.x;
    if (i == 0) *cnt = 0u;
    const float* src; unsigned short* dst; int j;
    if (i < 1048576)      { src = q;  dst = qb;  j = i; }
    else if (i < 2097152) { src = k;  dst = kb;  j = i - 1048576; }
    else if (i < 3145728) { src = v;  dst = vb;  j = i - 2097152; }
    else if (i < 3670016) { src = wq; dst = wqb; j = i - 3145728; }
    else if (i < 3801088) { src = wk; dst = wkvb; j = i - 3670016; }
    else if (i < 3932160) { src = wv; dst = wkvb + (size_t)KV_DIM * D_MODEL; j = i - 3801088; }
    else                  { src = wo; dst = wob; j = i - 3932160; }
    const float4* p = reinterpret_cast<const float4*>(src) + (size_t)j * 2;
    float4 a = p[0], b = p[1];
    union { unsigned short u[8]; uint4 v4; } r;
    r.u[0] = f2bf(a.x); r.u[1] = f2bf(a.y); r.u[2] = f2bf(a.z); r.u[3] = f2bf(a.w);
    r.u[4] = f2bf(b.x); r.u[5] = f2bf(b.y); r.u[6] = f2bf(b.z); r.u[7] = f2bf(b.w);
    reinterpret_cast<uint4*>(dst)[j] = r.v4;
}

// ---------------- 256x256 8-phase GEMM (C = A[M][K] * B[N][K]^T) ----------------
#define SCALE_Q 0.1803368867f   // 0.125 * log2(e)
#define GK 2048

template<int WHICH>
__global__ __launch_bounds__(512, 2) void gemm8(const unsigned short* __restrict__ Aq,
                                                const unsigned short* __restrict__ Ak,
                                                const unsigned short* __restrict__ Av,
                                                const unsigned short* __restrict__ Bq,
                                                const unsigned short* __restrict__ Bkv,
                                                unsigned short* __restrict__ out_q,
                                                unsigned short* __restrict__ out_k,
                                                unsigned short* __restrict__ out_v,
                                                float* __restrict__ out_f) {
    __shared__ __align__(16) char lds[131072];

    const int tid = threadIdx.x;
    const int lane = tid & 63;
    const int w = tid >> 6;
    const int wm = w >> 2, wn = w & 3;
    const int l15 = lane & 15, l4 = lane >> 4;

    const int nblk = (WHICH == 0) ? 192 : 128;
    int bid = blockIdx.x;
    bid = (bid & 7) * (nblk >> 3) + (bid >> 3);
    const int mb = bid & 15, nb = bid >> 4;
    const int m0 = mb * 256;

    const unsigned short* Ap;
    const unsigned short* Bp;
    int mode = 0, n0q = 0;
    if (WHICH == 1) {
        Ap = Aq; Bp = Bq + (size_t)(nb * 256) * GK; n0q = nb * 256;
    } else if (nb < 8) {
        Ap = Aq; Bp = Bq + (size_t)(nb * 256) * GK; mode = 0; n0q = nb * 256;
    } else if (nb < 10) {
        Ap = Ak; Bp = Bkv + (size_t)((nb - 8) * 256) * GK; mode = 1; n0q = (nb - 8) * 256;
    } else {
        Ap = Av; Bp = Bkv + (size_t)((nb - 10) * 256 + 512) * GK; mode = 2; n0q = (nb - 10) * 256;
    }

    const int srow = tid >> 3;
    const int gcol = (((tid & 7) * 16) ^ ((srow & 7) << 4)) >> 1;
    char* const myl = lds + tid * 16;

    auto stageA = [&](int tile, int half) {
        char* dst = myl + (tile & 1) * 32768 + half * 16384;
        const unsigned short* src = Ap + (size_t)(m0 + half * 128 + srow) * GK + tile * 64 + gcol;
        async_copy16(src, dst);
        async_copy16(src + (size_t)64 * GK, dst + 8192);
    };
    auto stageB = [&](int tile, int half) {
        char* dst = myl + 65536 + (tile & 1) * 32768 + half * 16384;
        const unsigned short* src = Bp + (size_t)(half * 128 + srow) * GK + tile * 64 + gcol;
        async_copy16(src, dst);
        async_copy16(src + (size_t)64 * GK, dst + 8192);
    };

    bf16x8 af[4][2], bf[4][2];
    auto loadA = [&](int buf, int mhalf) {
        const char* base = lds + buf * 32768;
#pragma unroll
        for (int mi = 0; mi < 4; ++mi) {
            const int r = wm * 128 + mhalf * 64 + mi * 16 + l15;
#pragma unroll
            for (int ks = 0; ks < 2; ++ks)
                af[mi][ks] = *reinterpret_cast<const bf16x8*>(
                    base + r * 128 + ((ks * 64 + l4 * 16) ^ ((r & 7) << 4)));
        }
    };
    auto loadB = [&](int buf, int nhalf) {
        const char* base = lds + 65536 + buf * 32768;
#pragma unroll
        for (int ni2 = 0; ni2 < 2; ++ni2) {
            const int ni = nhalf * 2 + ni2;
            const int r = wn * 64 + ni * 16 + l15;
#pragma unroll
            for (int ks = 0; ks < 2; ++ks)
                bf[ni][ks] = *reinterpret_cast<const bf16x8*>(
                    base + r * 128 + ((ks * 64 + l4 * 16) ^ ((r & 7) << 4)));
        }
    };

    f32x4 acc[8][4] = {};
    auto mfma16 = [&](int mq, int nq) {
        __builtin_amdgcn_s_setprio(1);
#pragma unroll
        for (int mi = 0; mi < 4; ++mi)
#pragma unroll
            for (int ni2 = 0; ni2 < 2; ++ni2)
#pragma unroll
                for (int ks = 0; ks < 2; ++ks)
                    acc[mq * 4 + mi][nq * 2 + ni2] = __builtin_amdgcn_mfma_f32_16x16x32_bf16(
                        af[mi][ks], bf[nq * 2 + ni2][ks], acc[mq * 4 + mi][nq * 2 + ni2], 0, 0, 0);
        __builtin_amdgcn_s_setprio(0);
    };

    stageA(0, 0); stageA(0, 1); stageB(0, 0); stageB(0, 1); stageB(1, 0); stageB(1, 1);
    asm volatile("s_waitcnt vmcnt(4)" ::: "memory");
    gbar();

    for (int i = 0; i < 16; ++i) {
        const int u = 2 * i;
        const bool nl = (i < 15);
        loadA(0, 0); loadB(0, 0); stageA(u + 1, 0);
        gbar(); lgkm0(); mfma16(0, 0); gbar();
        loadB(0, 1); stageA(u + 1, 1);
        gbar(); lgkm0(); mfma16(0, 1); gbar();
        loadA(0, 1); if (nl) stageB(u + 2, 0);
        gbar(); lgkm0(); mfma16(1, 0); gbar();
        if (nl) stageB(u + 2, 1);
        gbar(); mfma16(1, 1);
        if (nl) asm volatile("s_waitcnt vmcnt(4)" ::: "memory");
        else    asm volatile("s_waitcnt vmcnt(0)" ::: "memory");
        gbar();
        loadA(1, 0); loadB(1, 0); if (nl) stageA(u + 2, 0);
        gbar(); lgkm0(); mfma16(0, 0); gbar();
        loadB(1, 1); if (nl) stageA(u + 2, 1);
        gbar(); lgkm0(); mfma16(0, 1); gbar();
        loadA(1, 1); if (nl) stageB(u + 3, 0);
        gbar(); lgkm0(); mfma16(1, 0); gbar();
        if (nl) stageB(u + 3, 1);
        gbar(); mfma16(1, 1);
        if (nl) asm volatile("s_waitcnt vmcnt(4)" ::: "memory");
        gbar();
    }

    if (WHICH == 1) {
#pragma unroll
        for (int mi = 0; mi < 8; ++mi) {
            const int row = m0 + wm * 128 + mi * 16 + l4 * 4;
#pragma unroll
            for (int ni = 0; ni < 4; ++ni) {
                const int col = n0q + wn * 64 + ni * 16 + l15;
#pragma unroll
                for (int r = 0; r < 4; ++r)
                    out_f[(size_t)(row + r) * D_MODEL + col] = acc[mi][ni][r];
            }
        }
    } else if (mode == 0) {
#pragma unroll
        for (int mi = 0; mi < 8; ++mi) {
            const int row = m0 + wm * 128 + mi * 16 + l4 * 4;
#pragma unroll
            for (int ni = 0; ni < 4; ++ni) {
                const int col = n0q + wn * 64 + ni * 16 + l15;
#pragma unroll
                for (int r = 0; r < 4; ++r)
                    out_q[(size_t)(row + r) * D_MODEL + col] = f2bf(acc[mi][ni][r] * SCALE_Q);
            }
        }
    } else if (mode == 1) {
#pragma unroll
        for (int mi = 0; mi < 8; ++mi) {
            const int row = m0 + wm * 128 + mi * 16 + l4 * 4;
#pragma unroll
            for (int ni = 0; ni < 4; ++ni) {
                const int col = n0q + wn * 64 + ni * 16 + l15;
#pragma unroll
                for (int r = 0; r < 4; ++r)
                    out_k[(size_t)(row + r) * KV_DIM + col] = f2bf(acc[mi][ni][r]);
            }
        }
    } else {
        const int bb = m0 >> 11;
#pragma unroll
        for (int mi = 0; mi < 8; ++mi) {
            const int tok = (m0 & 2047) + wm * 128 + mi * 16 + l4 * 4;
#pragma unroll
            for (int ni = 0; ni < 4; ++ni) {
                const int c = n0q + wn * 64 + ni * 16 + l15;
                const int g = c >> 6, dh = c & 63;
                uint2 pk;
                pk.x = cvtpk(acc[mi][ni][0], acc[mi][ni][1]);
                pk.y = cvtpk(acc[mi][ni][2], acc[mi][ni][3]);
                *reinterpret_cast<uint2*>(out_v + (size_t)((bb * NG + g) * DHEAD + dh) * S_LEN + tok) = pk;
            }
        }
    }
}

// ---------------- flash attention v5: 32x32 MFMA, in-register softmax ----------------
// 8 waves x 32 q-rows (QBLK=256). Swapped QK^T via mfma_32x32x16(K, Q):
// S^T col = m = lane&31, row = t = (reg&3)+8*(reg>>2)+4*hi (hi = lane>>5).
// Softmax fully in registers (1 shfl_xor(32) per reduce). P -> PV B-fragment
// via 4 cvt_pk + 2 permlane32_swap per 16-k chunk (zero LDS for P).
// K/V LDS-staged, XOR-swizzled, double-buffered; 1 barrier per KV tile.
__constant__ unsigned char cls2_qi[12]   = {7,7,3,6,6,5,5,2,4,4,1,0};
__constant__ unsigned char cls2_half[12] = {0,1,0,0,1,0,1,0,0,1,0,0};

__global__ __launch_bounds__(512, 4) void attn3_kernel(const unsigned short* __restrict__ qp,
                                                       const unsigned short* __restrict__ kp,
                                                       const unsigned short* __restrict__ vpT,
                                                       unsigned short* __restrict__ attn_out,
                                                       unsigned int* __restrict__ counter,
                                                       unsigned short* __restrict__ partO,
                                                       float* __restrict__ ml) {
    __shared__ __align__(16) unsigned short Ks[2][KVB * 64];   // [t][dh] swz, 8KB each
    __shared__ __align__(16) unsigned short Vs[2][KVB * 64];   // [dh][t] swz, 8KB each
    __shared__ int s_item;

    const int tid = threadIdx.x;
    const int lane = tid & 63;
    const int w = tid >> 6;                 // 0..7
    const int l31 = lane & 31, hi = lane >> 5;
    const int sr = tid >> 3, sc = tid & 7;  // staging: row 0..63, chunk 0..7
    const int sgcol = (((sc * 16) ^ ((sr & 7) << 4)) >> 1);   // inverse-swz global col (elems)
    char* const kdst0 = (char*)Ks[0] + tid * 16;
    char* const kdst1 = (char*)Ks[1] + tid * 16;
    char* const vdst0 = (char*)Vs[0] + tid * 16;
    char* const vdst1 = (char*)Vs[1] + tid * 16;

    for (;;) {
        if (tid == 0) s_item = (int)atomicAdd(counter, 1u);
        __syncthreads();
        const int item = s_item;
        if (item >= N_ITEMS2) break;
        const int slot = item >> 6;
        const int bh = item & 63;
        const int qi = cls2_qi[slot];
        const int half = cls2_half[slot];
        const bool split = qi >= 4;
        const int b = bh >> 5, head = bh & 31, g = head >> 2;
        const int s0 = qi * QBLK;
        const int m = s0 + w * 32 + l31;        // this lane's query row
        const int mmaxw = s0 + w * 32 + 31;

        int j0, j1;
        if (split) { j0 = half * 2 * (qi + 1); j1 = j0 + 2 * (qi + 1); }
        else       { j0 = 0;                   j1 = 4 * (qi + 1); }

        // Q fragments: col m = l31, k = dh = 16*kstep + 8*hi + e (contiguous HW map)
        bf16x8 qf[4];
        {
            const unsigned short* qrow = qp + (size_t)(b * S_LEN + m) * D_MODEL + head * DHEAD + hi * 8;
#pragma unroll
            for (int k = 0; k < 4; ++k)
                qf[k] = *reinterpret_cast<const bf16x8*>(qrow + k * 16);
        }

        const unsigned short* kbase = kp + (size_t)(b * S_LEN + sr) * KV_DIM + g * DHEAD + sgcol;
        const unsigned short* vbase = vpT + (size_t)((b * NG + g) * DHEAD + sr) * S_LEN + sgcol;

        float mrun = -1e30f, lrun = 0.f;
        f32x16 o0 = {}, o1 = {};

        // prologue: stage tile j0 into buffer 0
        async_copy16(kbase + (size_t)j0 * KVB * KV_DIM, kdst0);
        async_copy16(vbase + j0 * KVB, vdst0);
        asm volatile("s_waitcnt vmcnt(0)" ::: "memory");
        gbar();

        for (int j = j0; j < j1; ++j) {
            const int cur = (j - j0) & 1;
            const int t0 = j * KVB;
            // issue next-tile staging into the other buffer (T14: overlaps compute)
            if (j + 1 < j1) {
                async_copy16(kbase + (size_t)(j + 1) * KVB * KV_DIM, cur ? kdst0 : kdst1);
                async_copy16(vbase + (j + 1) * KVB, cur ? vdst0 : vdst1);
            }

            const bool tt0 = (t0 <= mmaxw);
            const bool tt1 = (t0 + 32 <= mmaxw);
            if (tt0) {
                const char* Kb = (const char*)Ks[cur];
                const char* Vb = (const char*)Vs[cur];
                const int rswz0 = (l31 & 7) << 4;

                // ---- S^T = mfma_32x32x16(K, Q), 4 k-steps, 2 t-tiles ----
                f32x16 s0v = {}, s1v = {};
#pragma unroll
                for (int k = 0; k < 4; ++k) {
                    const int coff = k * 32 + hi * 16;
                    const bf16x8 kf0 = *reinterpret_cast<const bf16x8*>(
                        Kb + l31 * 128 + (coff ^ rswz0));
                    s0v = __builtin_amdgcn_mfma_f32_32x32x16_bf16(kf0, qf[k], s0v, 0, 0, 0);
                    if (tt1) {
                        const bf16x8 kf1 = *reinterpret_cast<const bf16x8*>(
                            Kb + (32 + l31) * 128 + (coff ^ rswz0));
                        s1v = __builtin_amdgcn_mfma_f32_32x32x16_bf16(kf1, qf[k], s1v, 0, 0, 0);
                    }
                }

                // ---- in-register online softmax (exp2 domain) ----
                const bool msk = (t0 + KVB - 1) > (s0 + w * 32);   // tile straddles diagonal
                float rmax = -1e30f;
#pragma unroll
                for (int r = 0; r < 16; ++r) {
                    const int tloc = (r & 3) + 8 * (r >> 2) + 4 * hi;
                    float v = s0v[r];
                    if (msk && (t0 + tloc > m)) v = -1e30f;
                    s0v[r] = v;
                    rmax = fmaxf(rmax, v);
                }
                if (tt1) {
#pragma unroll
                    for (int r = 0; r < 16; ++r) {
                        const int tloc = 32 + (r & 3) + 8 * (r >> 2) + 4 * hi;
                        float v = s1v[r];
                        if (msk && (t0 + tloc > m)) v = -1e30f;
                        s1v[r] = v;
                        rmax = fmaxf(rmax, v);
                    }
                }
                rmax = fmaxf(rmax, __shfl_xor(rmax, 32, 64));
                if (!__all(rmax <= mrun + 8.0f)) {   // T13 defer-max
                    const float mnew = fmaxf(mrun, rmax);
                    const float corr = __builtin_amdgcn_exp2f(mrun - mnew);
                    lrun *= corr;
#pragma unroll
                    for (int r = 0; r < 16; ++r) { o0[r] *= corr; o1[r] *= corr; }
                    mrun = mnew;
                }
                float rs = 0.f;
#pragma unroll
                for (int r = 0; r < 16; ++r) {
                    const float p = __builtin_amdgcn_exp2f(s0v[r] - mrun);
                    s0v[r] = p;
                    rs += p;
                }
                if (tt1) {
#pragma unroll
                    for (int r = 0; r < 16; ++r) {
                        const float p = __builtin_amdgcn_exp2f(s1v[r] - mrun);
                        s1v[r] = p;
                        rs += p;
                    }
                }
                rs += __shfl_xor(rs, 32, 64);
                lrun += rs;

                // ---- O^T += mfma_32x32x16(V, P); P built in-register ----
#pragma unroll
                for (int c = 0; c < 4; ++c) {
                    if (c >= 2 && !tt1) break;
                    const f32x16& sv = (c >> 1) ? s1v : s0v;
                    const int h8 = (c & 1) * 8;
                    uint32_t a0 = cvtpk(sv[h8 + 0], sv[h8 + 1]);
                    uint32_t a1 = cvtpk(sv[h8 + 2], sv[h8 + 3]);
                    uint32_t b0 = cvtpk(sv[h8 + 4], sv[h8 + 5]);
                    uint32_t b1 = cvtpk(sv[h8 + 6], sv[h8 + 7]);
                    plswap(a0, b0); plswap(a1, b1);
                    union { uint32_t w4[4]; bf16x8 v; } pf;
                    pf.w4[0] = a0; pf.w4[1] = a1; pf.w4[2] = b0; pf.w4[3] = b1;
                    const int coff = c * 32 + hi * 16;
                    const bf16x8 vf0 = *reinterpret_cast<const bf16x8*>(
                        Vb + l31 * 128 + (coff ^ rswz0));
                    o0 = __builtin_amdgcn_mfma_f32_32x32x16_bf16(vf0, pf.v, o0, 0, 0, 0);
                    const bf16x8 vf1 = *reinterpret_cast<const bf16x8*>(
                        Vb + (32 + l31) * 128 + (coff ^ rswz0));
                    o1 = __builtin_amdgcn_mfma_f32_32x32x16_bf16(vf1, pf.v, o1, 0, 0, 0);
                }
            }
            asm volatile("s_waitcnt vmcnt(0)" ::: "memory");
            gbar();   // next buffer staged & visible; current reads done
        }

        // ---- epilogue: lane owns row m, dh = 32*d + 8*q + 4*hi + 0..3 per reg quad ----
        if (split) {
            const int pb = ((bh << 2) + (qi - 4)) * 2 + half;
            const int mrow = w * 32 + l31;
            if (hi == 0) {
                ml[pb * 512 + mrow] = mrun;
                ml[pb * 512 + 256 + mrow] = lrun;
            }
            unsigned short* dst = partO + (size_t)pb * 16384 + mrow * 64 + hi * 4;
#pragma unroll
            for (int qd = 0; qd < 4; ++qd) {
                uint2 pk0, pk1;
                pk0.x = cvtpk(o0[4 * qd + 0], o0[4 * qd + 1]);
                pk0.y = cvtpk(o0[4 * qd + 2], o0[4 * qd + 3]);
                pk1.x = cvtpk(o1[4 * qd + 0], o1[4 * qd + 1]);
                pk1.y = cvtpk(o1[4 * qd + 2], o1[4 * qd + 3]);
                *reinterpret_cast<uint2*>(dst + 8 * qd) = pk0;
                *reinterpret_cast<uint2*>(dst + 32 + 8 * qd) = pk1;
            }
        } else {
            const float inv = 1.0f / lrun;
            unsigned short* dst = attn_out + (size_t)(b * S_LEN + m) * D_MODEL + head * DHEAD + hi * 4;
#pragma unroll
            for (int qd = 0; qd < 4; ++qd) {
                uint2 pk0, pk1;
                pk0.x = cvtpk(o0[4 * qd + 0] * inv, o0[4 * qd + 1] * inv);
                pk0.y = cvtpk(o0[4 * qd + 2] * inv, o0[4 * qd + 3] * inv);
                pk1.x = cvtpk(o1[4 * qd + 0] * inv, o1[4 * qd + 1] * inv);
                pk1.y = cvtpk(o1[4 * qd + 2] * inv, o1[4 * qd + 3] * inv);
                *reinterpret_cast<uint2*>(dst + 8 * qd) = pk0;
                *reinterpret_cast<uint2*>(dst + 32 + 8 * qd) = pk1;
            }
        }
    }
}

// ---------------- merge two KV-halves (qi>=4) ----------------
__global__ __launch_bounds__(512) void merge2_kernel(const unsigned short* __restrict__ partO,
                                                     const float* __restrict__ ml,
                                                     unsigned short* __restrict__ attn_out) {
    const int blk = blockIdx.x;          // bh*4 + (qi-4)
    const int bh = blk >> 2;
    const int qi = (blk & 3) + 4;
    const int b = bh >> 5, head = bh & 31;
    const int s0 = qi * QBLK;
    const int tid = threadIdx.x;
    const int row = tid >> 1, dh0 = (tid & 1) * 32;
    const int pb0 = blk * 2, pb1 = pb0 + 1;

    const float m0 = ml[pb0 * 512 + row], l0 = ml[pb0 * 512 + 256 + row];
    const float m1 = ml[pb1 * 512 + row], l1 = ml[pb1 * 512 + 256 + row];
    const float M = fmaxf(m0, m1);
    float w0 = __builtin_amdgcn_exp2f(m0 - M);
    float w1 = __builtin_amdgcn_exp2f(m1 - M);
    const float inv = 1.0f / (l0 * w0 + l1 * w1);
    w0 *= inv; w1 *= inv;

    const uint4* p0 = reinterpret_cast<const uint4*>(partO + (size_t)pb0 * 16384 + row * 64 + dh0);
    const uint4* p1 = reinterpret_cast<const uint4*>(partO + (size_t)pb1 * 16384 + row * 64 + dh0);
    unsigned short* dst = attn_out + (size_t)(b * S_LEN + s0 + row) * D_MODEL + head * DHEAD + dh0;
#pragma unroll
    for (int c = 0; c < 4; ++c) {
        union { unsigned short u[8]; uint4 v; } ua, ub, uo;
        ua.v = p0[c]; ub.v = p1[c];
#pragma unroll
        for (int e = 0; e < 8; e += 2) {
            float x0 = bf2f(ua.u[e]) * w0 + bf2f(ub.u[e]) * w1;
            float x1 = bf2f(ua.u[e + 1]) * w0 + bf2f(ub.u[e + 1]) * w1;
            reinterpret_cast<uint32_t*>(uo.u)[e >> 1] = cvtpk(x0, x1);
        }
        reinterpret_cast<uint4*>(dst)[c] = uo.v;
    }
}

// ---------------- host launch ----------------
extern "C" void kernel_launch(void* const* d_in, const int* in_sizes, int n_in,
                              void* d_out, int out_size, void* d_ws, size_t ws_size,
                              hipStream_t stream) {
    const float* q     = (const float*)d_in[0];
    const float* k     = (const float*)d_in[1];
    const float* v     = (const float*)d_in[2];
    const float* w_q   = (const float*)d_in[4];
    const float* w_k   = (const float*)d_in[5];
    const float* w_v   = (const float*)d_in[6];
    const float* w_out = (const float*)d_in[7];

    char* ws = (char*)d_ws;
    size_t off = 0;
    auto alloc = [&](size_t n) { char* p = ws + off; off += (n + 255) & ~(size_t)255; return p; };
    unsigned short* qb   = (unsigned short*)alloc((size_t)M_TOK * D_MODEL * 2);  // partO after proj
    unsigned short* kb   = (unsigned short*)alloc((size_t)M_TOK * D_MODEL * 2);
    unsigned short* vb   = (unsigned short*)alloc((size_t)M_TOK * D_MODEL * 2);
    unsigned short* wqb  = (unsigned short*)alloc((size_t)D_MODEL * D_MODEL * 2);
    unsigned short* wkvb = (unsigned short*)alloc((size_t)2 * KV_DIM * D_MODEL * 2);
    unsigned short* wob  = (unsigned short*)alloc((size_t)D_MODEL * D_MODEL * 2);
    unsigned short* qpb  = (unsigned short*)alloc((size_t)M_TOK * D_MODEL * 2);
    unsigned short* kpb  = (unsigned short*)alloc((size_t)M_TOK * KV_DIM * 2);
    unsigned short* vtb  = (unsigned short*)alloc((size_t)M_TOK * KV_DIM * 2);
    unsigned short* aob  = (unsigned short*)alloc((size_t)M_TOK * D_MODEL * 2);
    float*          mlb  = (float*)alloc((size_t)512 * 512 * 4);
    unsigned int*   cnt  = (unsigned int*)alloc(256);

    // single fused convert (also resets the attn work counter)
    cvt_all<<<dim3(17408), dim3(256), 0, stream>>>(q, k, v, w_q, w_k, w_v, w_out,
                                                   qb, kb, vb, wqb, wkvb, wob, cnt);

    // fused q/k/v projections: 192 blocks (q:128, k:32, v:32), 8-phase 256^2
    gemm8<0><<<dim3(192), dim3(512), 0, stream>>>(qb, kb, vb, wqb, wkvb, qpb, kpb, vtb, nullptr);

    // attention: 512 persistent blocks, 8 waves, 32x32 in-register softmax
    attn3_kernel<<<dim3(512), dim3(512), 0, stream>>>(qpb, kpb, vtb, aob, cnt, qb, mlb);
    merge2_kernel<<<dim3(256), dim3(512), 0, stream>>>(qb, mlb, aob);

    // output projection: 128 blocks, f32 out
    gemm8<1><<<dim3(128), dim3(512), 0, stream>>>(aob, nullptr, nullptr, wob, nullptr,
                                                  nullptr, nullptr, nullptr, (float*)d_out);
}

// Round 7
// 189.295 us; speedup vs baseline: 3.4221x; 1.1215x over previous
//
#include <hip/hip_runtime.h>
#include <hip/hip_bf16.h>
#include <stdint.h>

#define B_SZ 2
#define S_LEN 2048
#define D_MODEL 2048
#define NH 32
#define NG 8
#define HGRP 4
#define DHEAD 64
#define KV_DIM 512       // NG*DHEAD
#define M_TOK 4096       // B_SZ*S_LEN
#define KVB 64           // attention KV tile
#define QBLK 256
#define N_ITEMS2 768     // 12 slot-classes * 64 (b,head)

typedef __attribute__((ext_vector_type(8))) short bf16x8;
typedef __attribute__((ext_vector_type(4))) float f32x4;
typedef __attribute__((ext_vector_type(16))) float f32x16;

__device__ inline unsigned short f2bf(float x) {
    uint32_t u = __builtin_bit_cast(uint32_t, x);
    uint32_t r = (u + 0x7fffu + ((u >> 16) & 1u)) >> 16;
    return (unsigned short)r;
}

__device__ inline uint32_t cvtpk(float lo, float hi) {
    uint32_t r;
    asm("v_cvt_pk_bf16_f32 %0, %1, %2" : "=v"(r) : "v"(lo), "v"(hi));
    return r;
}

__device__ inline void plswap(uint32_t& a, uint32_t& b) {
    asm volatile("v_permlane32_swap_b32 %0, %1" : "+v"(a), "+v"(b));
}

__device__ inline float bf2f(unsigned short u) {
    uint32_t x = ((uint32_t)u) << 16;
    return __builtin_bit_cast(float, x);
}

__device__ inline void async_copy16(const void* g, void* l) {
    __builtin_amdgcn_global_load_lds(
        (const __attribute__((address_space(1))) void*)g,
        (__attribute__((address_space(3))) void*)l,
        16, 0, 0);
}

__device__ inline void gbar() {
    asm volatile("" ::: "memory");
    __builtin_amdgcn_s_barrier();
    asm volatile("" ::: "memory");
}
__device__ inline void lgkm0() {
    asm volatile("s_waitcnt lgkmcnt(0)" ::: "memory");
    __builtin_amdgcn_sched_barrier(0);
}

// ---------------- fused f32 -> bf16 convert (all 7 tensors) ----------------
__global__ __launch_bounds__(256) void cvt_all(const float* __restrict__ q,
                                               const float* __restrict__ k,
                                               const float* __restrict__ v,
                                               const float* __restrict__ wq,
                                               const float* __restrict__ wk,
                                               const float* __restrict__ wv,
                                               const float* __restrict__ wo,
                                               unsigned short* __restrict__ qb,
                                               unsigned short* __restrict__ kb,
                                               unsigned short* __restrict__ vb,
                                               unsigned short* __restrict__ wqb,
                                               unsigned short* __restrict__ wkvb,
                                               unsigned short* __restrict__ wob,
                                               unsigned int* __restrict__ cnt) {
    const int i = blockIdx.x * 256 + threadIdx.x;
    if (i == 0) *cnt = 0u;
    const float* src; unsigned short* dst; int j;
    if (i < 1048576)      { src = q;  dst = qb;  j = i; }
    else if (i < 2097152) { src = k;  dst = kb;  j = i - 1048576; }
    else if (i < 3145728) { src = v;  dst = vb;  j = i - 2097152; }
    else if (i < 3670016) { src = wq; dst = wqb; j = i - 3145728; }
    else if (i < 3801088) { src = wk; dst = wkvb; j = i - 3670016; }
    else if (i < 3932160) { src = wv; dst = wkvb + (size_t)KV_DIM * D_MODEL; j = i - 3801088; }
    else                  { src = wo; dst = wob; j = i - 3932160; }
    const float4* p = reinterpret_cast<const float4*>(src) + (size_t)j * 2;
    float4 a = p[0], b = p[1];
    union { unsigned short u[8]; uint4 v4; } r;
    r.u[0] = f2bf(a.x); r.u[1] = f2bf(a.y); r.u[2] = f2bf(a.z); r.u[3] = f2bf(a.w);
    r.u[4] = f2bf(b.x); r.u[5] = f2bf(b.y); r.u[6] = f2bf(b.z); r.u[7] = f2bf(b.w);
    reinterpret_cast<uint4*>(dst)[j] = r.v4;
}

#define SCALE_Q 0.1803368867f   // 0.125 * log2(e)
#define GK 2048

// ---------------- proj GEMM: 256x256 8-phase, N-stacked q|k|v ----------------
__global__ __launch_bounds__(512, 2) void gemm8p(const unsigned short* __restrict__ Aq,
                                                 const unsigned short* __restrict__ Ak,
                                                 const unsigned short* __restrict__ Av,
                                                 const unsigned short* __restrict__ Bq,
                                                 const unsigned short* __restrict__ Bkv,
                                                 unsigned short* __restrict__ out_q,
                                                 unsigned short* __restrict__ out_k,
                                                 unsigned short* __restrict__ out_v) {
    __shared__ __align__(16) char lds[131072];

    const int tid = threadIdx.x;
    const int lane = tid & 63;
    const int w = tid >> 6;
    const int wm = w >> 2, wn = w & 3;
    const int l15 = lane & 15, l4 = lane >> 4;

    int bid = blockIdx.x;
    bid = (bid & 7) * 24 + (bid >> 3);      // bijective XCD swizzle, 192 blocks
    const int mb = bid & 15, nb = bid >> 4;
    const int m0 = mb * 256;

    const unsigned short* Ap;
    const unsigned short* Bp;
    int mode = 0, n0q = 0;
    if (nb < 8) {
        Ap = Aq; Bp = Bq + (size_t)(nb * 256) * GK; mode = 0; n0q = nb * 256;
    } else if (nb < 10) {
        Ap = Ak; Bp = Bkv + (size_t)((nb - 8) * 256) * GK; mode = 1; n0q = (nb - 8) * 256;
    } else {
        Ap = Av; Bp = Bkv + (size_t)((nb - 10) * 256 + 512) * GK; mode = 2; n0q = (nb - 10) * 256;
    }

    const int srow = tid >> 3;
    const int gcol = (((tid & 7) * 16) ^ ((srow & 7) << 4)) >> 1;
    char* const myl = lds + tid * 16;

    auto stageA = [&](int tile, int half) {
        char* dst = myl + (tile & 1) * 32768 + half * 16384;
        const unsigned short* src = Ap + (size_t)(m0 + half * 128 + srow) * GK + tile * 64 + gcol;
        async_copy16(src, dst);
        async_copy16(src + (size_t)64 * GK, dst + 8192);
    };
    auto stageB = [&](int tile, int half) {
        char* dst = myl + 65536 + (tile & 1) * 32768 + half * 16384;
        const unsigned short* src = Bp + (size_t)(half * 128 + srow) * GK + tile * 64 + gcol;
        async_copy16(src, dst);
        async_copy16(src + (size_t)64 * GK, dst + 8192);
    };

    bf16x8 af[4][2], bf[4][2];
    auto loadA = [&](int buf, int mhalf) {
        const char* base = lds + buf * 32768;
#pragma unroll
        for (int mi = 0; mi < 4; ++mi) {
            const int r = wm * 128 + mhalf * 64 + mi * 16 + l15;
#pragma unroll
            for (int ks = 0; ks < 2; ++ks)
                af[mi][ks] = *reinterpret_cast<const bf16x8*>(
                    base + r * 128 + ((ks * 64 + l4 * 16) ^ ((r & 7) << 4)));
        }
    };
    auto loadB = [&](int buf, int nhalf) {
        const char* base = lds + 65536 + buf * 32768;
#pragma unroll
        for (int ni2 = 0; ni2 < 2; ++ni2) {
            const int ni = nhalf * 2 + ni2;
            const int r = wn * 64 + ni * 16 + l15;
#pragma unroll
            for (int ks = 0; ks < 2; ++ks)
                bf[ni][ks] = *reinterpret_cast<const bf16x8*>(
                    base + r * 128 + ((ks * 64 + l4 * 16) ^ ((r & 7) << 4)));
        }
    };

    f32x4 acc[8][4] = {};
    auto mfma16 = [&](int mq, int nq) {
        __builtin_amdgcn_s_setprio(1);
#pragma unroll
        for (int mi = 0; mi < 4; ++mi)
#pragma unroll
            for (int ni2 = 0; ni2 < 2; ++ni2)
#pragma unroll
                for (int ks = 0; ks < 2; ++ks)
                    acc[mq * 4 + mi][nq * 2 + ni2] = __builtin_amdgcn_mfma_f32_16x16x32_bf16(
                        af[mi][ks], bf[nq * 2 + ni2][ks], acc[mq * 4 + mi][nq * 2 + ni2], 0, 0, 0);
        __builtin_amdgcn_s_setprio(0);
    };

    stageA(0, 0); stageA(0, 1); stageB(0, 0); stageB(0, 1); stageB(1, 0); stageB(1, 1);
    asm volatile("s_waitcnt vmcnt(4)" ::: "memory");
    gbar();

    for (int i = 0; i < 16; ++i) {
        const int u = 2 * i;
        const bool nl = (i < 15);
        loadA(0, 0); loadB(0, 0); stageA(u + 1, 0);
        gbar(); lgkm0(); mfma16(0, 0); gbar();
        loadB(0, 1); stageA(u + 1, 1);
        gbar(); lgkm0(); mfma16(0, 1); gbar();
        loadA(0, 1); if (nl) stageB(u + 2, 0);
        gbar(); lgkm0(); mfma16(1, 0); gbar();
        if (nl) stageB(u + 2, 1);
        gbar(); mfma16(1, 1);
        if (nl) asm volatile("s_waitcnt vmcnt(4)" ::: "memory");
        else    asm volatile("s_waitcnt vmcnt(0)" ::: "memory");
        gbar();
        loadA(1, 0); loadB(1, 0); if (nl) stageA(u + 2, 0);
        gbar(); lgkm0(); mfma16(0, 0); gbar();
        loadB(1, 1); if (nl) stageA(u + 2, 1);
        gbar(); lgkm0(); mfma16(0, 1); gbar();
        loadA(1, 1); if (nl) stageB(u + 3, 0);
        gbar(); lgkm0(); mfma16(1, 0); gbar();
        if (nl) stageB(u + 3, 1);
        gbar(); mfma16(1, 1);
        if (nl) asm volatile("s_waitcnt vmcnt(4)" ::: "memory");
        gbar();
    }

    if (mode == 0) {
#pragma unroll
        for (int mi = 0; mi < 8; ++mi) {
            const int row = m0 + wm * 128 + mi * 16 + l4 * 4;
#pragma unroll
            for (int ni = 0; ni < 4; ++ni) {
                const int col = n0q + wn * 64 + ni * 16 + l15;
#pragma unroll
                for (int r = 0; r < 4; ++r)
                    out_q[(size_t)(row + r) * D_MODEL + col] = f2bf(acc[mi][ni][r] * SCALE_Q);
            }
        }
    } else if (mode == 1) {
#pragma unroll
        for (int mi = 0; mi < 8; ++mi) {
            const int row = m0 + wm * 128 + mi * 16 + l4 * 4;
#pragma unroll
            for (int ni = 0; ni < 4; ++ni) {
                const int col = n0q + wn * 64 + ni * 16 + l15;
#pragma unroll
                for (int r = 0; r < 4; ++r)
                    out_k[(size_t)(row + r) * KV_DIM + col] = f2bf(acc[mi][ni][r]);
            }
        }
    } else {
        const int bb = m0 >> 11;
#pragma unroll
        for (int mi = 0; mi < 8; ++mi) {
            const int tok = (m0 & 2047) + wm * 128 + mi * 16 + l4 * 4;
#pragma unroll
            for (int ni = 0; ni < 4; ++ni) {
                const int c = n0q + wn * 64 + ni * 16 + l15;
                const int g = c >> 6, dh = c & 63;
                uint2 pk;
                pk.x = cvtpk(acc[mi][ni][0], acc[mi][ni][1]);
                pk.y = cvtpk(acc[mi][ni][2], acc[mi][ni][3]);
                *reinterpret_cast<uint2*>(out_v + (size_t)((bb * NG + g) * DHEAD + dh) * S_LEN + tok) = pk;
            }
        }
    }
}

// ---------------- out-proj GEMM: 256x128 8-phase, grid 256 = full GPU ----------------
// BM=256, BN=128, 8 waves in 4x2 grid (wave tile 64x64). stageB = 1 load/thread
// so steady-state counted wait is vmcnt(2) (= 2 x B_LOADS). LDS 96 KB.
__global__ __launch_bounds__(512, 1) void gemm8o(const unsigned short* __restrict__ A,
                                                 const unsigned short* __restrict__ B,
                                                 float* __restrict__ C) {
    __shared__ __align__(16) char lds[98304];   // A:[0,64K) dbuf 32K; B:[64K,96K) dbuf 16K

    const int tid = threadIdx.x;
    const int lane = tid & 63;
    const int w = tid >> 6;
    const int wm = w >> 1, wn = w & 1;
    const int l15 = lane & 15, l4 = lane >> 4;

    int bid = blockIdx.x;
    bid = (bid & 7) * 32 + (bid >> 3);      // bijective XCD swizzle, 256 blocks
    const int mb = bid & 15, nb = bid >> 4;
    const int m0 = mb * 256, n0 = nb * 128;
    const unsigned short* Bp = B + (size_t)n0 * GK;

    const int srow = tid >> 3;
    const int gcol = (((tid & 7) * 16) ^ ((srow & 7) << 4)) >> 1;

    auto stageA = [&](int tile, int half) {
        char* dst = lds + (tile & 1) * 32768 + half * 16384 + tid * 16;
        const unsigned short* src = A + (size_t)(m0 + half * 128 + srow) * GK + tile * 64 + gcol;
        async_copy16(src, dst);
        async_copy16(src + (size_t)64 * GK, dst + 8192);
    };
    auto stageB = [&](int tile, int half) {
        char* dst = lds + 65536 + (tile & 1) * 16384 + half * 8192 + tid * 16;
        const unsigned short* src = Bp + (size_t)(half * 64 + srow) * GK + tile * 64 + gcol;
        async_copy16(src, dst);
    };

    bf16x8 af[2][2], bf[4][2];
    auto loadA2 = [&](int buf, int mhalf) {
        const char* base = lds + buf * 32768;
#pragma unroll
        for (int mi = 0; mi < 2; ++mi) {
            const int r = wm * 64 + mhalf * 32 + mi * 16 + l15;
#pragma unroll
            for (int ks = 0; ks < 2; ++ks)
                af[mi][ks] = *reinterpret_cast<const bf16x8*>(
                    base + r * 128 + ((ks * 64 + l4 * 16) ^ ((r & 7) << 4)));
        }
    };
    auto loadB2 = [&](int buf, int nhalf) {
        const char* base = lds + 65536 + buf * 16384;
#pragma unroll
        for (int ni2 = 0; ni2 < 2; ++ni2) {
            const int ni = nhalf * 2 + ni2;
            const int r = wn * 64 + ni * 16 + l15;
#pragma unroll
            for (int ks = 0; ks < 2; ++ks)
                bf[ni][ks] = *reinterpret_cast<const bf16x8*>(
                    base + r * 128 + ((ks * 64 + l4 * 16) ^ ((r & 7) << 4)));
        }
    };

    f32x4 acc[4][4] = {};
    auto mfma8 = [&](int mq, int nq) {
        __builtin_amdgcn_s_setprio(1);
#pragma unroll
        for (int mi = 0; mi < 2; ++mi)
#pragma unroll
            for (int ni2 = 0; ni2 < 2; ++ni2)
#pragma unroll
                for (int ks = 0; ks < 2; ++ks)
                    acc[mq * 2 + mi][nq * 2 + ni2] = __builtin_amdgcn_mfma_f32_16x16x32_bf16(
                        af[mi][ks], bf[nq * 2 + ni2][ks], acc[mq * 2 + mi][nq * 2 + ni2], 0, 0, 0);
        __builtin_amdgcn_s_setprio(0);
    };

    stageA(0, 0); stageA(0, 1); stageB(0, 0); stageB(0, 1); stageB(1, 0); stageB(1, 1);
    asm volatile("s_waitcnt vmcnt(2)" ::: "memory");
    gbar();

    for (int i = 0; i < 16; ++i) {
        const int u = 2 * i;
        const bool nl = (i < 15);
        loadA2(0, 0); loadB2(0, 0); stageA(u + 1, 0);
        gbar(); lgkm0(); mfma8(0, 0); gbar();
        loadB2(0, 1); stageA(u + 1, 1);
        gbar(); lgkm0(); mfma8(0, 1); gbar();
        loadA2(0, 1); if (nl) stageB(u + 2, 0);
        gbar(); lgkm0(); mfma8(1, 0); gbar();
        if (nl) stageB(u + 2, 1);
        gbar(); mfma8(1, 1);
        if (nl) asm volatile("s_waitcnt vmcnt(2)" ::: "memory");
        else    asm volatile("s_waitcnt vmcnt(0)" ::: "memory");
        gbar();
        loadA2(1, 0); loadB2(1, 0); if (nl) stageA(u + 2, 0);
        gbar(); lgkm0(); mfma8(0, 0); gbar();
        loadB2(1, 1); if (nl) stageA(u + 2, 1);
        gbar(); lgkm0(); mfma8(0, 1); gbar();
        loadA2(1, 1); if (nl) stageB(u + 3, 0);
        gbar(); lgkm0(); mfma8(1, 0); gbar();
        if (nl) stageB(u + 3, 1);
        gbar(); mfma8(1, 1);
        if (nl) asm volatile("s_waitcnt vmcnt(2)" ::: "memory");
        gbar();
    }

#pragma unroll
    for (int mi = 0; mi < 4; ++mi) {
        const int row = m0 + wm * 64 + mi * 16 + l4 * 4;
#pragma unroll
        for (int ni = 0; ni < 4; ++ni) {
            const int col = n0 + wn * 64 + ni * 16 + l15;
#pragma unroll
            for (int r = 0; r < 4; ++r)
                C[(size_t)(row + r) * D_MODEL + col] = acc[mi][ni][r];
        }
    }
}

// ---------------- flash attention: 32x32 MFMA, in-register softmax ----------------
__constant__ unsigned char cls2_qi[12]   = {7,7,3,6,6,5,5,2,4,4,1,0};
__constant__ unsigned char cls2_half[12] = {0,1,0,0,1,0,1,0,0,1,0,0};

__global__ __launch_bounds__(512, 4) void attn3_kernel(const unsigned short* __restrict__ qp,
                                                       const unsigned short* __restrict__ kp,
                                                       const unsigned short* __restrict__ vpT,
                                                       unsigned short* __restrict__ attn_out,
                                                       unsigned int* __restrict__ counter,
                                                       unsigned short* __restrict__ partO,
                                                       float* __restrict__ ml) {
    __shared__ __align__(16) unsigned short Ks[2][KVB * 64];
    __shared__ __align__(16) unsigned short Vs[2][KVB * 64];
    __shared__ int s_item;

    const int tid = threadIdx.x;
    const int lane = tid & 63;
    const int w = tid >> 6;
    const int l31 = lane & 31, hi = lane >> 5;
    const int sr = tid >> 3, sc = tid & 7;
    const int sgcol = (((sc * 16) ^ ((sr & 7) << 4)) >> 1);
    char* const kdst0 = (char*)Ks[0] + tid * 16;
    char* const kdst1 = (char*)Ks[1] + tid * 16;
    char* const vdst0 = (char*)Vs[0] + tid * 16;
    char* const vdst1 = (char*)Vs[1] + tid * 16;

    for (;;) {
        if (tid == 0) s_item = (int)atomicAdd(counter, 1u);
        __syncthreads();
        const int item = s_item;
        if (item >= N_ITEMS2) break;
        const int slot = item >> 6;
        const int bh = item & 63;
        const int qi = cls2_qi[slot];
        const int half = cls2_half[slot];
        const bool split = qi >= 4;
        const int b = bh >> 5, head = bh & 31, g = head >> 2;
        const int s0 = qi * QBLK;
        const int m = s0 + w * 32 + l31;
        const int mmaxw = s0 + w * 32 + 31;

        int j0, j1;
        if (split) { j0 = half * 2 * (qi + 1); j1 = j0 + 2 * (qi + 1); }
        else       { j0 = 0;                   j1 = 4 * (qi + 1); }

        bf16x8 qf[4];
        {
            const unsigned short* qrow = qp + (size_t)(b * S_LEN + m) * D_MODEL + head * DHEAD + hi * 8;
#pragma unroll
            for (int k = 0; k < 4; ++k)
                qf[k] = *reinterpret_cast<const bf16x8*>(qrow + k * 16);
        }

        const unsigned short* kbase = kp + (size_t)(b * S_LEN + sr) * KV_DIM + g * DHEAD + sgcol;
        const unsigned short* vbase = vpT + (size_t)((b * NG + g) * DHEAD + sr) * S_LEN + sgcol;

        float mrun = -1e30f, lrun = 0.f;
        f32x16 o0 = {}, o1 = {};

        async_copy16(kbase + (size_t)j0 * KVB * KV_DIM, kdst0);
        async_copy16(vbase + j0 * KVB, vdst0);
        asm volatile("s_waitcnt vmcnt(0)" ::: "memory");
        gbar();

        for (int j = j0; j < j1; ++j) {
            const int cur = (j - j0) & 1;
            const int t0 = j * KVB;
            if (j + 1 < j1) {
                async_copy16(kbase + (size_t)(j + 1) * KVB * KV_DIM, cur ? kdst0 : kdst1);
                async_copy16(vbase + (j + 1) * KVB, cur ? vdst0 : vdst1);
            }

            const bool tt0 = (t0 <= mmaxw);
            const bool tt1 = (t0 + 32 <= mmaxw);
            if (tt0) {
                const char* Kb = (const char*)Ks[cur];
                const char* Vb = (const char*)Vs[cur];
                const int rswz0 = (l31 & 7) << 4;

                // ---- S^T = mfma_32x32x16(K, Q) ----
                f32x16 s0v = {}, s1v = {};
#pragma unroll
                for (int k = 0; k < 4; ++k) {
                    const int coff = k * 32 + hi * 16;
                    const bf16x8 kf0 = *reinterpret_cast<const bf16x8*>(
                        Kb + l31 * 128 + (coff ^ rswz0));
                    s0v = __builtin_amdgcn_mfma_f32_32x32x16_bf16(kf0, qf[k], s0v, 0, 0, 0);
                    if (tt1) {
                        const bf16x8 kf1 = *reinterpret_cast<const bf16x8*>(
                            Kb + (32 + l31) * 128 + (coff ^ rswz0));
                        s1v = __builtin_amdgcn_mfma_f32_32x32x16_bf16(kf1, qf[k], s1v, 0, 0, 0);
                    }
                }

                // ---- in-register online softmax (mask hoisted: wave-uniform branch) ----
                const bool msk = (t0 + KVB - 1) > (s0 + w * 32);
                float rmax = -1e30f;
                if (msk) {
#pragma unroll
                    for (int r = 0; r < 16; ++r) {
                        const int tloc = (r & 3) + 8 * (r >> 2) + 4 * hi;
                        float v = s0v[r];
                        if (t0 + tloc > m) v = -1e30f;
                        s0v[r] = v;
                        rmax = fmaxf(rmax, v);
                    }
                    if (tt1) {
#pragma unroll
                        for (int r = 0; r < 16; ++r) {
                            const int tloc = 32 + (r & 3) + 8 * (r >> 2) + 4 * hi;
                            float v = s1v[r];
                            if (t0 + tloc > m) v = -1e30f;
                            s1v[r] = v;
                            rmax = fmaxf(rmax, v);
                        }
                    }
                } else {
#pragma unroll
                    for (int r = 0; r < 16; ++r)
                        rmax = fmaxf(rmax, s0v[r]);
                    if (tt1) {
#pragma unroll
                        for (int r = 0; r < 16; ++r)
                            rmax = fmaxf(rmax, s1v[r]);
                    }
                }
                rmax = fmaxf(rmax, __shfl_xor(rmax, 32, 64));
                if (!__all(rmax <= mrun + 8.0f)) {   // T13 defer-max
                    const float mnew = fmaxf(mrun, rmax);
                    const float corr = __builtin_amdgcn_exp2f(mrun - mnew);
                    lrun *= corr;
#pragma unroll
                    for (int r = 0; r < 16; ++r) { o0[r] *= corr; o1[r] *= corr; }
                    mrun = mnew;
                }
                float rs = 0.f;
#pragma unroll
                for (int r = 0; r < 16; ++r) {
                    const float p = __builtin_amdgcn_exp2f(s0v[r] - mrun);
                    s0v[r] = p;
                    rs += p;
                }
                if (tt1) {
#pragma unroll
                    for (int r = 0; r < 16; ++r) {
                        const float p = __builtin_amdgcn_exp2f(s1v[r] - mrun);
                        s1v[r] = p;
                        rs += p;
                    }
                }
                rs += __shfl_xor(rs, 32, 64);
                lrun += rs;

                // ---- O^T += mfma_32x32x16(V, P); P built in-register ----
#pragma unroll
                for (int c = 0; c < 4; ++c) {
                    if (c >= 2 && !tt1) break;
                    const f32x16& sv = (c >> 1) ? s1v : s0v;
                    const int h8 = (c & 1) * 8;
                    uint32_t a0 = cvtpk(sv[h8 + 0], sv[h8 + 1]);
                    uint32_t a1 = cvtpk(sv[h8 + 2], sv[h8 + 3]);
                    uint32_t b0 = cvtpk(sv[h8 + 4], sv[h8 + 5]);
                    uint32_t b1 = cvtpk(sv[h8 + 6], sv[h8 + 7]);
                    plswap(a0, b0); plswap(a1, b1);
                    union { uint32_t w4[4]; bf16x8 v; } pf;
                    pf.w4[0] = a0; pf.w4[1] = a1; pf.w4[2] = b0; pf.w4[3] = b1;
                    const int coff = c * 32 + hi * 16;
                    const bf16x8 vf0 = *reinterpret_cast<const bf16x8*>(
                        Vb + l31 * 128 + (coff ^ rswz0));
                    o0 = __builtin_amdgcn_mfma_f32_32x32x16_bf16(vf0, pf.v, o0, 0, 0, 0);
                    const bf16x8 vf1 = *reinterpret_cast<const bf16x8*>(
                        Vb + (32 + l31) * 128 + (coff ^ rswz0));
                    o1 = __builtin_amdgcn_mfma_f32_32x32x16_bf16(vf1, pf.v, o1, 0, 0, 0);
                }
            }
            asm volatile("s_waitcnt vmcnt(0)" ::: "memory");
            gbar();
        }

        if (split) {
            const int pb = ((bh << 2) + (qi - 4)) * 2 + half;
            const int mrow = w * 32 + l31;
            if (hi == 0) {
                ml[pb * 512 + mrow] = mrun;
                ml[pb * 512 + 256 + mrow] = lrun;
            }
            unsigned short* dst = partO + (size_t)pb * 16384 + mrow * 64 + hi * 4;
#pragma unroll
            for (int qd = 0; qd < 4; ++qd) {
                uint2 pk0, pk1;
                pk0.x = cvtpk(o0[4 * qd + 0], o0[4 * qd + 1]);
                pk0.y = cvtpk(o0[4 * qd + 2], o0[4 * qd + 3]);
                pk1.x = cvtpk(o1[4 * qd + 0], o1[4 * qd + 1]);
                pk1.y = cvtpk(o1[4 * qd + 2], o1[4 * qd + 3]);
                *reinterpret_cast<uint2*>(dst + 8 * qd) = pk0;
                *reinterpret_cast<uint2*>(dst + 32 + 8 * qd) = pk1;
            }
        } else {
            const float inv = 1.0f / lrun;
            unsigned short* dst = attn_out + (size_t)(b * S_LEN + m) * D_MODEL + head * DHEAD + hi * 4;
#pragma unroll
            for (int qd = 0; qd < 4; ++qd) {
                uint2 pk0, pk1;
                pk0.x = cvtpk(o0[4 * qd + 0] * inv, o0[4 * qd + 1] * inv);
                pk0.y = cvtpk(o0[4 * qd + 2] * inv, o0[4 * qd + 3] * inv);
                pk1.x = cvtpk(o1[4 * qd + 0] * inv, o1[4 * qd + 1] * inv);
                pk1.y = cvtpk(o1[4 * qd + 2] * inv, o1[4 * qd + 3] * inv);
                *reinterpret_cast<uint2*>(dst + 8 * qd) = pk0;
                *reinterpret_cast<uint2*>(dst + 32 + 8 * qd) = pk1;
            }
        }
    }
}

// ---------------- merge two KV-halves (qi>=4) ----------------
__global__ __launch_bounds__(512) void merge2_kernel(const unsigned short* __restrict__ partO,
                                                     const float* __restrict__ ml,
                                                     unsigned short* __restrict__ attn_out) {
    const int blk = blockIdx.x;
    const int bh = blk >> 2;
    const int qi = (blk & 3) + 4;
    const int b = bh >> 5, head = bh & 31;
    const int s0 = qi * QBLK;
    const int tid = threadIdx.x;
    const int row = tid >> 1, dh0 = (tid & 1) * 32;
    const int pb0 = blk * 2, pb1 = pb0 + 1;

    const float m0 = ml[pb0 * 512 + row], l0 = ml[pb0 * 512 + 256 + row];
    const float m1 = ml[pb1 * 512 + row], l1 = ml[pb1 * 512 + 256 + row];
    const float M = fmaxf(m0, m1);
    float w0 = __builtin_amdgcn_exp2f(m0 - M);
    float w1 = __builtin_amdgcn_exp2f(m1 - M);
    const float inv = 1.0f / (l0 * w0 + l1 * w1);
    w0 *= inv; w1 *= inv;

    const uint4* p0 = reinterpret_cast<const uint4*>(partO + (size_t)pb0 * 16384 + row * 64 + dh0);
    const uint4* p1 = reinterpret_cast<const uint4*>(partO + (size_t)pb1 * 16384 + row * 64 + dh0);
    unsigned short* dst = attn_out + (size_t)(b * S_LEN + s0 + row) * D_MODEL + head * DHEAD + dh0;
#pragma unroll
    for (int c = 0; c < 4; ++c) {
        union { unsigned short u[8]; uint4 v; } ua, ub, uo;
        ua.v = p0[c]; ub.v = p1[c];
#pragma unroll
        for (int e = 0; e < 8; e += 2) {
            float x0 = bf2f(ua.u[e]) * w0 + bf2f(ub.u[e]) * w1;
            float x1 = bf2f(ua.u[e + 1]) * w0 + bf2f(ub.u[e + 1]) * w1;
            reinterpret_cast<uint32_t*>(uo.u)[e >> 1] = cvtpk(x0, x1);
        }
        reinterpret_cast<uint4*>(dst)[c] = uo.v;
    }
}

// ---------------- host launch ----------------
extern "C" void kernel_launch(void* const* d_in, const int* in_sizes, int n_in,
                              void* d_out, int out_size, void* d_ws, size_t ws_size,
                              hipStream_t stream) {
    const float* q     = (const float*)d_in[0];
    const float* k     = (const float*)d_in[1];
    const float* v     = (const float*)d_in[2];
    const float* w_q   = (const float*)d_in[4];
    const float* w_k   = (const float*)d_in[5];
    const float* w_v   = (const float*)d_in[6];
    const float* w_out = (const float*)d_in[7];

    char* ws = (char*)d_ws;
    size_t off = 0;
    auto alloc = [&](size_t n) { char* p = ws + off; off += (n + 255) & ~(size_t)255; return p; };
    unsigned short* qb   = (unsigned short*)alloc((size_t)M_TOK * D_MODEL * 2);  // partO after proj
    unsigned short* kb   = (unsigned short*)alloc((size_t)M_TOK * D_MODEL * 2);
    unsigned short* vb   = (unsigned short*)alloc((size_t)M_TOK * D_MODEL * 2);
    unsigned short* wqb  = (unsigned short*)alloc((size_t)D_MODEL * D_MODEL * 2);
    unsigned short* wkvb = (unsigned short*)alloc((size_t)2 * KV_DIM * D_MODEL * 2);
    unsigned short* wob  = (unsigned short*)alloc((size_t)D_MODEL * D_MODEL * 2);
    unsigned short* qpb  = (unsigned short*)alloc((size_t)M_TOK * D_MODEL * 2);
    unsigned short* kpb  = (unsigned short*)alloc((size_t)M_TOK * KV_DIM * 2);
    unsigned short* vtb  = (unsigned short*)alloc((size_t)M_TOK * KV_DIM * 2);
    unsigned short* aob  = (unsigned short*)alloc((size_t)M_TOK * D_MODEL * 2);
    float*          mlb  = (float*)alloc((size_t)512 * 512 * 4);
    unsigned int*   cnt  = (unsigned int*)alloc(256);

    cvt_all<<<dim3(17408), dim3(256), 0, stream>>>(q, k, v, w_q, w_k, w_v, w_out,
                                                   qb, kb, vb, wqb, wkvb, wob, cnt);

    gemm8p<<<dim3(192), dim3(512), 0, stream>>>(qb, kb, vb, wqb, wkvb, qpb, kpb, vtb);

    attn3_kernel<<<dim3(768), dim3(512), 0, stream>>>(qpb, kpb, vtb, aob, cnt, qb, mlb);
    merge2_kernel<<<dim3(256), dim3(512), 0, stream>>>(qb, mlb, aob);

    gemm8o<<<dim3(256), dim3(512), 0, stream>>>(aob, wob, (float*)d_out);
}